// Round 3
// baseline (2578.993 us; speedup 1.0000x reference)
//
#include <hip/hip_runtime.h>
#include <math.h>

#define N_NODES 10000
#define F_IN_D  256
#define H_DIM   128
#define C_OUTD  40
#define NHEADS  8
#define NEDGES  160000
#define ETOT    (NEDGES + N_NODES)
#define SCALE_F 0.25f  /* 1/sqrt(16) */
#define TILES_N 157    /* ceil(10000/64) */

__device__ __forceinline__ unsigned short f2bf(float f) {
    unsigned int u = __float_as_uint(f);
    unsigned int r = (u + 0x7FFFu + ((u >> 16) & 1u)) >> 16;  // RNE
    return (unsigned short)r;
}
__device__ __forceinline__ float bf2f(unsigned short h) {
    return __uint_as_float(((unsigned int)h) << 16);
}

// ---------------- graph preprocessing ----------------

__global__ void k_deg_init(int* degi) {
    int i = blockIdx.x * 256 + threadIdx.x;
    if (i < N_NODES) degi[i] = 1;  // self-loop
}

__global__ void k_deg_count(const int* __restrict__ col, int* degi) {
    int e = blockIdx.x * 256 + threadIdx.x;
    if (e < NEDGES) atomicAdd(&degi[col[e]], 1);
}

// single-block exclusive scan over degrees -> CSR offsets; zeroes cursors
// 250 threads x 40 entries covers 10000 exactly; int4-vectorized reads
__global__ void k_scan(const int* __restrict__ degi, int* offsets, int* cursor) {
    __shared__ int part[256];
    int tid = threadIdx.x;
    int s = 0;
    if (tid < 250) {
        const int4* d4 = (const int4*)degi;
        #pragma unroll
        for (int i = 0; i < 10; ++i) {
            int4 v = d4[tid * 10 + i];
            s += v.x + v.y + v.z + v.w;
        }
    }
    part[tid] = s;
    __syncthreads();
    for (int off = 1; off < 256; off <<= 1) {
        int v = 0;
        if (tid >= off) v = part[tid - off];
        __syncthreads();
        part[tid] += v;
        __syncthreads();
    }
    if (tid < 250) {
        int base = part[tid] - s;  // exclusive prefix
        int beg = tid * 40;
        for (int i = 0; i < 40; ++i) {
            offsets[beg + i] = base;
            cursor[beg + i]  = 0;
            base += degi[beg + i];
        }
    }
}

__global__ void k_scatter(const int* __restrict__ row, const int* __restrict__ col,
                          const int* __restrict__ degi, const int* __restrict__ offsets,
                          int* cursor, int* csr_row, float* csr_norm) {
    int e = blockIdx.x * 256 + threadIdx.x;
    if (e >= ETOT) return;
    int r, c;
    if (e < NEDGES) { r = row[e]; c = col[e]; }
    else            { r = c = e - NEDGES; }   // self-loop
    int slot = offsets[c] + atomicAdd(&cursor[c], 1);
    float dr = rsqrtf((float)degi[r]);
    float dc = rsqrtf((float)degi[c]);
    csr_row[slot]  = r;
    csr_norm[slot] = dr * dc;
}

// ---------------- generic fp32 GEMM (used for lin1) ----------------
// C[M x 128] = relu(A[M x Kd] @ W[Kd x 128] + b); tile 64 x 128, 256 thr

__global__ __launch_bounds__(256) void k_gemm(const float* __restrict__ A,
                                              const float* __restrict__ W,
                                              const float* __restrict__ bias,
                                              float* __restrict__ C,
                                              int M, int Kd, int do_relu) {
    __shared__ float As[64][68];
    __shared__ float Ws[64][128];
    int tid = threadIdx.x;
    int row0 = blockIdx.x * 64;
    int tr = tid >> 5;
    int tc = tid & 31;

    float acc[8][4];
    #pragma unroll
    for (int i = 0; i < 8; ++i)
        #pragma unroll
        for (int j = 0; j < 4; ++j) acc[i][j] = 0.f;

    for (int k0 = 0; k0 < Kd; k0 += 64) {
        #pragma unroll
        for (int it = 0; it < 4; ++it) {
            int f = tid + 256 * it;
            int r = f >> 4, kv = f & 15;
            float4 a4 = make_float4(0.f, 0.f, 0.f, 0.f);
            int ar = row0 + r;
            if (ar < M) a4 = *(const float4*)&A[(size_t)ar * Kd + k0 + kv * 4];
            *(float4*)&As[r][kv * 4] = a4;
        }
        #pragma unroll
        for (int it = 0; it < 8; ++it) {
            int f = tid + 256 * it;
            int kr = f >> 5, cv = f & 31;
            *(float4*)&Ws[kr][cv * 4] = *(const float4*)&W[(size_t)(k0 + kr) * H_DIM + cv * 4];
        }
        __syncthreads();
        #pragma unroll
        for (int kk = 0; kk < 64; kk += 4) {
            float4 w0 = *(const float4*)&Ws[kk + 0][tc * 4];
            float4 w1 = *(const float4*)&Ws[kk + 1][tc * 4];
            float4 w2 = *(const float4*)&Ws[kk + 2][tc * 4];
            float4 w3 = *(const float4*)&Ws[kk + 3][tc * 4];
            #pragma unroll
            for (int i = 0; i < 8; ++i) {
                float4 a = *(const float4*)&As[tr * 8 + i][kk];
                acc[i][0] += a.x * w0.x + a.y * w1.x + a.z * w2.x + a.w * w3.x;
                acc[i][1] += a.x * w0.y + a.y * w1.y + a.z * w2.y + a.w * w3.y;
                acc[i][2] += a.x * w0.z + a.y * w1.z + a.z * w2.z + a.w * w3.z;
                acc[i][3] += a.x * w0.w + a.y * w1.w + a.z * w2.w + a.w * w3.w;
            }
        }
        __syncthreads();
    }

    float4 b4 = *(const float4*)&bias[tc * 4];
    #pragma unroll
    for (int i = 0; i < 8; ++i) {
        int r = row0 + tr * 8 + i;
        if (r < M) {
            float4 o;
            o.x = acc[i][0] + b4.x; o.y = acc[i][1] + b4.y;
            o.z = acc[i][2] + b4.z; o.w = acc[i][3] + b4.w;
            if (do_relu) {
                o.x = fmaxf(o.x, 0.f); o.y = fmaxf(o.y, 0.f);
                o.z = fmaxf(o.z, 0.f); o.w = fmaxf(o.w, 0.f);
            }
            *(float4*)&C[(size_t)r * H_DIM + tc * 4] = o;
        }
    }
}

// ---------------- fused per-layer QKV projection ----------------
// One dispatch computes Q (fp32, slice l), K and V (bf16, slices 0..t-1).
// grid = (1+2t)*TILES_N blocks.  K/V layout: [node][slice(3)][128] bf16.

__global__ __launch_bounds__(256) void k_qkv(const float* __restrict__ XH,
                                             const float* __restrict__ wq,
                                             const float* __restrict__ wk,
                                             const float* __restrict__ wv,
                                             const float* __restrict__ bq,
                                             const float* __restrict__ bk,
                                             const float* __restrict__ bv,
                                             float* __restrict__ Qb,
                                             unsigned short* __restrict__ Kb,
                                             unsigned short* __restrict__ Vb,
                                             int l, int t) {
    __shared__ float As[64][68];
    __shared__ float Ws[64][128];
    int tid = threadIdx.x;
    int m  = blockIdx.x / TILES_N;   // 0 = Q; 1..t = K slice m-1; t+1..2t = V slice m-t-1
    int rt = blockIdx.x % TILES_N;
    const float* W; const float* bias; int slice; int mode;
    if (m == 0)      { W = wq; bias = bq; slice = l;         mode = 0; }
    else if (m <= t) { W = wk; bias = bk; slice = m - 1;     mode = 1; }
    else             { W = wv; bias = bv; slice = m - t - 1; mode = 2; }
    const float* A = XH + (size_t)slice * N_NODES * H_DIM;
    int row0 = rt * 64;
    int tr = tid >> 5;
    int tc = tid & 31;

    float acc[8][4];
    #pragma unroll
    for (int i = 0; i < 8; ++i)
        #pragma unroll
        for (int j = 0; j < 4; ++j) acc[i][j] = 0.f;

    #pragma unroll
    for (int k0 = 0; k0 < H_DIM; k0 += 64) {
        #pragma unroll
        for (int it = 0; it < 4; ++it) {
            int f = tid + 256 * it;
            int r = f >> 4, kv = f & 15;
            float4 a4 = make_float4(0.f, 0.f, 0.f, 0.f);
            int ar = row0 + r;
            if (ar < N_NODES) a4 = *(const float4*)&A[(size_t)ar * H_DIM + k0 + kv * 4];
            *(float4*)&As[r][kv * 4] = a4;
        }
        #pragma unroll
        for (int it = 0; it < 8; ++it) {
            int f = tid + 256 * it;
            int kr = f >> 5, cv = f & 31;
            *(float4*)&Ws[kr][cv * 4] = *(const float4*)&W[(size_t)(k0 + kr) * H_DIM + cv * 4];
        }
        __syncthreads();
        #pragma unroll
        for (int kk = 0; kk < 64; kk += 4) {
            float4 w0 = *(const float4*)&Ws[kk + 0][tc * 4];
            float4 w1 = *(const float4*)&Ws[kk + 1][tc * 4];
            float4 w2 = *(const float4*)&Ws[kk + 2][tc * 4];
            float4 w3 = *(const float4*)&Ws[kk + 3][tc * 4];
            #pragma unroll
            for (int i = 0; i < 8; ++i) {
                float4 a = *(const float4*)&As[tr * 8 + i][kk];
                acc[i][0] += a.x * w0.x + a.y * w1.x + a.z * w2.x + a.w * w3.x;
                acc[i][1] += a.x * w0.y + a.y * w1.y + a.z * w2.y + a.w * w3.y;
                acc[i][2] += a.x * w0.z + a.y * w1.z + a.z * w2.z + a.w * w3.z;
                acc[i][3] += a.x * w0.w + a.y * w1.w + a.z * w2.w + a.w * w3.w;
            }
        }
        __syncthreads();
    }

    float4 b4 = *(const float4*)&bias[tc * 4];
    unsigned short* OutB = (mode == 1) ? Kb : Vb;
    #pragma unroll
    for (int i = 0; i < 8; ++i) {
        int r = row0 + tr * 8 + i;
        if (r < N_NODES) {
            float4 o;
            o.x = acc[i][0] + b4.x; o.y = acc[i][1] + b4.y;
            o.z = acc[i][2] + b4.z; o.w = acc[i][3] + b4.w;
            if (mode == 0) {
                *(float4*)&Qb[(size_t)r * H_DIM + tc * 4] = o;
            } else {
                ushort4 p;
                p.x = f2bf(o.x); p.y = f2bf(o.y); p.z = f2bf(o.z); p.w = f2bf(o.w);
                *(ushort4*)&OutB[((size_t)r * 3 + slice) * H_DIM + tc * 4] = p;
            }
        }
    }
}

// ---------------- fused per-node attention aggregation ----------------
// one block (128 threads = 8 heads x 16 dims) per destination node
// K,V: bf16, layout [node][slice(3)][128]

template <int T>
__global__ __launch_bounds__(128) void k_attn_agg(const float* __restrict__ Q,
                                                  const unsigned short* __restrict__ K,
                                                  const unsigned short* __restrict__ V,
                                                  const int* __restrict__ csr_row,
                                                  const float* __restrict__ csr_norm,
                                                  const int* __restrict__ offsets,
                                                  const int* __restrict__ degi,
                                                  float* __restrict__ Xout) {
    int n = blockIdx.x;
    int tid = threadIdx.x;               // h = tid>>4, d = tid&15
    float qv = Q[(size_t)n * H_DIM + tid] * SCALE_F;
    int start = offsets[n];
    int cnt   = degi[n];
    float acc = 0.f;

    for (int j = 0; j < cnt; ++j) {
        int   r   = csr_row[start + j];
        float nrm = csr_norm[start + j];
        const unsigned short* kp = K + (size_t)r * 3 * H_DIM + tid;
        const unsigned short* vp = V + (size_t)r * 3 * H_DIM + tid;
        float sc[T];
        #pragma unroll
        for (int s = 0; s < T; ++s) {
            float p = qv * bf2f(kp[s * H_DIM]);
            p += __shfl_xor(p, 1, 16);
            p += __shfl_xor(p, 2, 16);
            p += __shfl_xor(p, 4, 16);
            p += __shfl_xor(p, 8, 16);
            sc[s] = p;                   // all 16 lanes hold the head-dot
        }
        float m = 0.f;
        #pragma unroll
        for (int s = 0; s < T; ++s) m = fmaxf(m, sc[s]);
        float den = expf(-m);            // restricted-softmax null slot
        float mv = 0.f;
        #pragma unroll
        for (int s = 0; s < T; ++s) {
            float wgt = expf(sc[s] - m);
            den += wgt;
            mv  += wgt * bf2f(vp[s * H_DIM]);
        }
        acc += nrm * mv / den;
    }
    Xout[(size_t)n * H_DIM + tid] = fmaxf(acc, 0.f);  // relu
}

// ---------------- fused lin2 + log_softmax ----------------

__global__ __launch_bounds__(256) void k_lin2(const float* __restrict__ X,
                                              const float* __restrict__ W2,
                                              const float* __restrict__ b2,
                                              float* __restrict__ out) {
    int lane = threadIdx.x & 63;
    int n = blockIdx.x * 4 + (threadIdx.x >> 6);
    if (n >= N_NODES) return;            // whole wave exits together
    float acc = (lane < C_OUTD) ? b2[lane] : 0.f;
    for (int k = 0; k < H_DIM; ++k) {
        float xv = X[(size_t)n * H_DIM + k];
        if (lane < C_OUTD) acc += xv * W2[k * C_OUTD + lane];
    }
    float lg = (lane < C_OUTD) ? acc : -INFINITY;
    float m = lg;
    #pragma unroll
    for (int o = 32; o > 0; o >>= 1) m = fmaxf(m, __shfl_xor(m, o, 64));
    float e = (lane < C_OUTD) ? expf(lg - m) : 0.f;
    float ssum = e;
    #pragma unroll
    for (int o = 32; o > 0; o >>= 1) ssum += __shfl_xor(ssum, o, 64);
    float lse = m + logf(ssum);
    if (lane < C_OUTD) out[(size_t)n * C_OUTD + lane] = lg - lse;
}

// ---------------- launcher ----------------

extern "C" void kernel_launch(void* const* d_in, const int* in_sizes, int n_in,
                              void* d_out, int out_size, void* d_ws, size_t ws_size,
                              hipStream_t stream) {
    const int*   ei      = (const int*)d_in[0];
    const int*   row     = ei;
    const int*   col     = ei + NEDGES;
    const float* x_param = (const float*)d_in[1];
    const float* lin1_w  = (const float*)d_in[2];
    const float* lin1_b  = (const float*)d_in[3];
    const float* wq      = (const float*)d_in[4];
    const float* wk      = (const float*)d_in[5];
    const float* wv      = (const float*)d_in[6];
    const float* bq      = (const float*)d_in[7];
    const float* bk      = (const float*)d_in[8];
    const float* bv      = (const float*)d_in[9];
    const float* lin2_w  = (const float*)d_in[10];
    const float* lin2_b  = (const float*)d_in[11];
    float*       out     = (float*)d_out;

    char* wbase = (char*)d_ws;
    size_t off = 0;
    auto alloc = [&](size_t bytes) -> void* {
        off = (off + 255) & ~(size_t)255;
        void* p = wbase + off;
        off += bytes;
        return p;
    };
    int*            degi     = (int*)           alloc((size_t)N_NODES * 4);
    int*            offsets  = (int*)           alloc((size_t)N_NODES * 4);
    int*            cursor   = (int*)           alloc((size_t)N_NODES * 4);
    int*            csr_row  = (int*)           alloc((size_t)ETOT * 4);
    float*          csr_norm = (float*)         alloc((size_t)ETOT * 4);
    float*          XH       = (float*)         alloc((size_t)4 * N_NODES * H_DIM * 4);
    float*          Qb       = (float*)         alloc((size_t)N_NODES * H_DIM * 4);
    unsigned short* Kb       = (unsigned short*)alloc((size_t)N_NODES * 3 * H_DIM * 2);
    unsigned short* Vb       = (unsigned short*)alloc((size_t)N_NODES * 3 * H_DIM * 2);

    // graph preprocessing (shared by all 3 layers)
    k_deg_init <<<(N_NODES + 255) / 256, 256, 0, stream>>>(degi);
    k_deg_count<<<(NEDGES + 255) / 256, 256, 0, stream>>>(col, degi);
    k_scan     <<<1, 256, 0, stream>>>(degi, offsets, cursor);
    k_scatter  <<<(ETOT + 255) / 256, 256, 0, stream>>>(row, col, degi, offsets, cursor,
                                                        csr_row, csr_norm);

    // x0 = relu(x_param @ lin1_w + lin1_b)
    k_gemm<<<TILES_N, 256, 0, stream>>>(x_param, lin1_w, lin1_b, XH, N_NODES, F_IN_D, 1);

    for (int l = 0; l < 3; ++l) {
        int t = l + 1;
        k_qkv<<<(1 + 2 * t) * TILES_N, 256, 0, stream>>>(
            XH,
            wq + (size_t)l * H_DIM * H_DIM, wk + (size_t)l * H_DIM * H_DIM,
            wv + (size_t)l * H_DIM * H_DIM,
            bq + l * H_DIM, bk + l * H_DIM, bv + l * H_DIM,
            Qb, Kb, Vb, l, t);
        float* Xnext = XH + (size_t)(l + 1) * N_NODES * H_DIM;
        if (t == 1)
            k_attn_agg<1><<<N_NODES, 128, 0, stream>>>(Qb, Kb, Vb, csr_row, csr_norm,
                                                       offsets, degi, Xnext);
        else if (t == 2)
            k_attn_agg<2><<<N_NODES, 128, 0, stream>>>(Qb, Kb, Vb, csr_row, csr_norm,
                                                       offsets, degi, Xnext);
        else
            k_attn_agg<3><<<N_NODES, 128, 0, stream>>>(Qb, Kb, Vb, csr_row, csr_norm,
                                                       offsets, degi, Xnext);
    }

    k_lin2<<<(N_NODES + 3) / 4, 256, 0, stream>>>(XH + (size_t)3 * N_NODES * H_DIM,
                                                  lin2_w, lin2_b, out);
}

// Round 7
// 531.822 us; speedup vs baseline: 4.8494x; 4.8494x over previous
//
#include <hip/hip_runtime.h>
#include <math.h>

#define N_NODES 10000
#define F_IN_D  256
#define H_DIM   128
#define C_OUTD  40
#define NHEADS  8
#define NEDGES  160000
#define ETOT    (NEDGES + N_NODES)
#define SCALE_F 0.25f  /* 1/sqrt(16) */
#define TILES_N 157    /* ceil(10000/64) */

__device__ __forceinline__ unsigned short f2bf(float f) {
    unsigned int u = __float_as_uint(f);
    unsigned int r = (u + 0x7FFFu + ((u >> 16) & 1u)) >> 16;  // RNE
    return (unsigned short)r;
}
__device__ __forceinline__ float bf2f(unsigned short h) {
    return __uint_as_float(((unsigned int)h) << 16);
}

// ---------------- graph preprocessing ----------------

__global__ void k_deg_init(int* degi) {
    int i = blockIdx.x * 256 + threadIdx.x;
    if (i < N_NODES) degi[i] = 1;  // self-loop
}

__global__ void k_deg_count(const int* __restrict__ col, int* degi) {
    int e = blockIdx.x * 256 + threadIdx.x;
    if (e < NEDGES) atomicAdd(&degi[col[e]], 1);
}

// single-block exclusive scan over degrees -> CSR offsets; zeroes cursors
__global__ void k_scan(const int* __restrict__ degi, int* offsets, int* cursor) {
    __shared__ int part[256];
    int tid = threadIdx.x;
    int s = 0;
    if (tid < 250) {
        const int4* d4 = (const int4*)degi;
        for (int i = 0; i < 10; ++i) {
            int4 v = d4[tid * 10 + i];
            s += v.x + v.y + v.z + v.w;
        }
    }
    part[tid] = s;
    __syncthreads();
    for (int off = 1; off < 256; off <<= 1) {
        int v = 0;
        if (tid >= off) v = part[tid - off];
        __syncthreads();
        part[tid] += v;
        __syncthreads();
    }
    if (tid < 250) {
        int base = part[tid] - s;  // exclusive prefix
        int beg = tid * 40;
        for (int i = 0; i < 40; ++i) {
            offsets[beg + i] = base;
            cursor[beg + i]  = 0;
            base += degi[beg + i];
        }
    }
}

__global__ void k_scatter(const int* __restrict__ row, const int* __restrict__ col,
                          const int* __restrict__ degi, const int* __restrict__ offsets,
                          int* cursor, int* csr_row, float* csr_norm) {
    int e = blockIdx.x * 256 + threadIdx.x;
    if (e >= ETOT) return;
    int r, c;
    if (e < NEDGES) { r = row[e]; c = col[e]; }
    else            { r = c = e - NEDGES; }   // self-loop
    int slot = offsets[c] + atomicAdd(&cursor[c], 1);
    float dr = rsqrtf((float)degi[r]);
    float dc = rsqrtf((float)degi[c]);
    csr_row[slot]  = r;
    csr_norm[slot] = dr * dc;
}

// ---------------- generic fp32 GEMM (used for lin1) ----------------
// Runtime Kd keeps the k0 loop un-unrolled (known-good round-2 body).

__global__ __launch_bounds__(256) void k_gemm(const float* __restrict__ A,
                                              const float* __restrict__ W,
                                              const float* __restrict__ bias,
                                              float* __restrict__ C,
                                              int M, int Kd, int do_relu) {
    __shared__ float As[64][68];
    __shared__ float Ws[64][128];
    int tid = threadIdx.x;
    int row0 = blockIdx.x * 64;
    int tr = tid >> 5;
    int tc = tid & 31;

    float acc[8][4];
    #pragma unroll
    for (int i = 0; i < 8; ++i)
        #pragma unroll
        for (int j = 0; j < 4; ++j) acc[i][j] = 0.f;

    for (int k0 = 0; k0 < Kd; k0 += 64) {
        #pragma unroll
        for (int it = 0; it < 4; ++it) {
            int f = tid + 256 * it;
            int r = f >> 4, kv = f & 15;
            float4 a4 = make_float4(0.f, 0.f, 0.f, 0.f);
            int ar = row0 + r;
            if (ar < M) a4 = *(const float4*)&A[(size_t)ar * Kd + k0 + kv * 4];
            *(float4*)&As[r][kv * 4] = a4;
        }
        #pragma unroll
        for (int it = 0; it < 8; ++it) {
            int f = tid + 256 * it;
            int kr = f >> 5, cv = f & 31;
            *(float4*)&Ws[kr][cv * 4] = *(const float4*)&W[(size_t)(k0 + kr) * H_DIM + cv * 4];
        }
        __syncthreads();
        #pragma unroll
        for (int kk = 0; kk < 64; kk += 4) {
            float4 w0 = *(const float4*)&Ws[kk + 0][tc * 4];
            float4 w1 = *(const float4*)&Ws[kk + 1][tc * 4];
            float4 w2 = *(const float4*)&Ws[kk + 2][tc * 4];
            float4 w3 = *(const float4*)&Ws[kk + 3][tc * 4];
            #pragma unroll
            for (int i = 0; i < 8; ++i) {
                float4 a = *(const float4*)&As[tr * 8 + i][kk];
                acc[i][0] += a.x * w0.x + a.y * w1.x + a.z * w2.x + a.w * w3.x;
                acc[i][1] += a.x * w0.y + a.y * w1.y + a.z * w2.y + a.w * w3.y;
                acc[i][2] += a.x * w0.z + a.y * w1.z + a.z * w2.z + a.w * w3.z;
                acc[i][3] += a.x * w0.w + a.y * w1.w + a.z * w2.w + a.w * w3.w;
            }
        }
        __syncthreads();
    }

    float4 b4 = *(const float4*)&bias[tc * 4];
    #pragma unroll
    for (int i = 0; i < 8; ++i) {
        int r = row0 + tr * 8 + i;
        if (r < M) {
            float4 o;
            o.x = acc[i][0] + b4.x; o.y = acc[i][1] + b4.y;
            o.z = acc[i][2] + b4.z; o.w = acc[i][3] + b4.w;
            if (do_relu) {
                o.x = fmaxf(o.x, 0.f); o.y = fmaxf(o.y, 0.f);
                o.z = fmaxf(o.z, 0.f); o.w = fmaxf(o.w, 0.f);
            }
            *(float4*)&C[(size_t)r * H_DIM + tc * 4] = o;
        }
    }
}

// ---------------- fused per-layer QKV projection ----------------
// One dispatch computes Q (fp32, slice l), K and V (bf16, slices 0..t-1).
// grid = (1+2t)*TILES_N blocks.  K/V layout: [node][slice(3)][128] bf16.
// Kd is a RUNTIME arg (always 128): unknown trip count structurally prevents
// the full-unroll register spill seen in round 3 (VGPR=256, 1.2 GB scratch,
// 2.9% VALUBusy, 1030 us/dispatch).

__global__ __launch_bounds__(256) void k_qkv(const float* __restrict__ XH,
                                             const float* __restrict__ wq,
                                             const float* __restrict__ wk,
                                             const float* __restrict__ wv,
                                             const float* __restrict__ bq,
                                             const float* __restrict__ bk,
                                             const float* __restrict__ bv,
                                             float* __restrict__ Qb,
                                             unsigned short* __restrict__ Kb,
                                             unsigned short* __restrict__ Vb,
                                             int l, int t, int Kd) {
    __shared__ float As[64][68];
    __shared__ float Ws[64][128];
    int tid = threadIdx.x;
    int m  = blockIdx.x / TILES_N;   // 0 = Q; 1..t = K slice m-1; t+1..2t = V slice m-t-1
    int rt = blockIdx.x % TILES_N;
    const float* W; const float* bias; int slice; int mode;
    if (m == 0)      { W = wq; bias = bq; slice = l;         mode = 0; }
    else if (m <= t) { W = wk; bias = bk; slice = m - 1;     mode = 1; }
    else             { W = wv; bias = bv; slice = m - t - 1; mode = 2; }
    const float* A = XH + (size_t)slice * N_NODES * H_DIM;
    int row0 = rt * 64;
    int tr = tid >> 5;
    int tc = tid & 31;

    float acc[8][4];
    #pragma unroll
    for (int i = 0; i < 8; ++i)
        #pragma unroll
        for (int j = 0; j < 4; ++j) acc[i][j] = 0.f;

    for (int k0 = 0; k0 < Kd; k0 += 64) {
        #pragma unroll
        for (int it = 0; it < 4; ++it) {
            int f = tid + 256 * it;
            int r = f >> 4, kv = f & 15;
            float4 a4 = make_float4(0.f, 0.f, 0.f, 0.f);
            int ar = row0 + r;
            if (ar < N_NODES) a4 = *(const float4*)&A[(size_t)ar * H_DIM + k0 + kv * 4];
            *(float4*)&As[r][kv * 4] = a4;
        }
        #pragma unroll
        for (int it = 0; it < 8; ++it) {
            int f = tid + 256 * it;
            int kr = f >> 5, cv = f & 31;
            *(float4*)&Ws[kr][cv * 4] = *(const float4*)&W[(size_t)(k0 + kr) * H_DIM + cv * 4];
        }
        __syncthreads();
        #pragma unroll
        for (int kk = 0; kk < 64; kk += 4) {
            float4 w0 = *(const float4*)&Ws[kk + 0][tc * 4];
            float4 w1 = *(const float4*)&Ws[kk + 1][tc * 4];
            float4 w2 = *(const float4*)&Ws[kk + 2][tc * 4];
            float4 w3 = *(const float4*)&Ws[kk + 3][tc * 4];
            #pragma unroll
            for (int i = 0; i < 8; ++i) {
                float4 a = *(const float4*)&As[tr * 8 + i][kk];
                acc[i][0] += a.x * w0.x + a.y * w1.x + a.z * w2.x + a.w * w3.x;
                acc[i][1] += a.x * w0.y + a.y * w1.y + a.z * w2.y + a.w * w3.y;
                acc[i][2] += a.x * w0.z + a.y * w1.z + a.z * w2.z + a.w * w3.z;
                acc[i][3] += a.x * w0.w + a.y * w1.w + a.z * w2.w + a.w * w3.w;
            }
        }
        __syncthreads();
    }

    float4 b4 = *(const float4*)&bias[tc * 4];
    unsigned short* OutB = (mode == 1) ? Kb : Vb;
    #pragma unroll
    for (int i = 0; i < 8; ++i) {
        int r = row0 + tr * 8 + i;
        if (r < N_NODES) {
            float4 o;
            o.x = acc[i][0] + b4.x; o.y = acc[i][1] + b4.y;
            o.z = acc[i][2] + b4.z; o.w = acc[i][3] + b4.w;
            if (mode == 0) {
                *(float4*)&Qb[(size_t)r * H_DIM + tc * 4] = o;
            } else {
                ushort4 p;
                p.x = f2bf(o.x); p.y = f2bf(o.y); p.z = f2bf(o.z); p.w = f2bf(o.w);
                *(ushort4*)&OutB[((size_t)r * 3 + slice) * H_DIM + tc * 4] = p;
            }
        }
    }
}

// ---------------- fused per-node attention aggregation ----------------
// one block (128 threads = 8 heads x 16 dims) per destination node
// K,V: bf16, layout [node][slice(3)][128]

template <int T>
__global__ __launch_bounds__(128) void k_attn_agg(const float* __restrict__ Q,
                                                  const unsigned short* __restrict__ K,
                                                  const unsigned short* __restrict__ V,
                                                  const int* __restrict__ csr_row,
                                                  const float* __restrict__ csr_norm,
                                                  const int* __restrict__ offsets,
                                                  const int* __restrict__ degi,
                                                  float* __restrict__ Xout) {
    int n = blockIdx.x;
    int tid = threadIdx.x;               // h = tid>>4, d = tid&15
    float qv = Q[(size_t)n * H_DIM + tid] * SCALE_F;
    int start = offsets[n];
    int cnt   = degi[n];
    float acc = 0.f;

    for (int j = 0; j < cnt; ++j) {
        int   r   = csr_row[start + j];
        float nrm = csr_norm[start + j];
        const unsigned short* kp = K + (size_t)r * 3 * H_DIM + tid;
        const unsigned short* vp = V + (size_t)r * 3 * H_DIM + tid;
        float sc[T];
        #pragma unroll
        for (int s = 0; s < T; ++s) {
            float p = qv * bf2f(kp[s * H_DIM]);
            p += __shfl_xor(p, 1, 16);
            p += __shfl_xor(p, 2, 16);
            p += __shfl_xor(p, 4, 16);
            p += __shfl_xor(p, 8, 16);
            sc[s] = p;                   // all 16 lanes hold the head-dot
        }
        float m = 0.f;
        #pragma unroll
        for (int s = 0; s < T; ++s) m = fmaxf(m, sc[s]);
        float den = expf(-m);            // restricted-softmax null slot
        float mv = 0.f;
        #pragma unroll
        for (int s = 0; s < T; ++s) {
            float wgt = expf(sc[s] - m);
            den += wgt;
            mv  += wgt * bf2f(vp[s * H_DIM]);
        }
        acc += nrm * mv / den;
    }
    Xout[(size_t)n * H_DIM + tid] = fmaxf(acc, 0.f);  // relu
}

// ---------------- fused lin2 + log_softmax ----------------

__global__ __launch_bounds__(256) void k_lin2(const float* __restrict__ X,
                                              const float* __restrict__ W2,
                                              const float* __restrict__ b2,
                                              float* __restrict__ out) {
    int lane = threadIdx.x & 63;
    int n = blockIdx.x * 4 + (threadIdx.x >> 6);
    if (n >= N_NODES) return;            // whole wave exits together
    float acc = (lane < C_OUTD) ? b2[lane] : 0.f;
    for (int k = 0; k < H_DIM; ++k) {
        float xv = X[(size_t)n * H_DIM + k];
        if (lane < C_OUTD) acc += xv * W2[k * C_OUTD + lane];
    }
    float lg = (lane < C_OUTD) ? acc : -INFINITY;
    float m = lg;
    #pragma unroll
    for (int o = 32; o > 0; o >>= 1) m = fmaxf(m, __shfl_xor(m, o, 64));
    float e = (lane < C_OUTD) ? expf(lg - m) : 0.f;
    float ssum = e;
    #pragma unroll
    for (int o = 32; o > 0; o >>= 1) ssum += __shfl_xor(ssum, o, 64);
    float lse = m + logf(ssum);
    if (lane < C_OUTD) out[(size_t)n * C_OUTD + lane] = lg - lse;
}

// ---------------- launcher ----------------

extern "C" void kernel_launch(void* const* d_in, const int* in_sizes, int n_in,
                              void* d_out, int out_size, void* d_ws, size_t ws_size,
                              hipStream_t stream) {
    const int*   ei      = (const int*)d_in[0];
    const int*   row     = ei;
    const int*   col     = ei + NEDGES;
    const float* x_param = (const float*)d_in[1];
    const float* lin1_w  = (const float*)d_in[2];
    const float* lin1_b  = (const float*)d_in[3];
    const float* wq      = (const float*)d_in[4];
    const float* wk      = (const float*)d_in[5];
    const float* wv      = (const float*)d_in[6];
    const float* bq      = (const float*)d_in[7];
    const float* bk      = (const float*)d_in[8];
    const float* bv      = (const float*)d_in[9];
    const float* lin2_w  = (const float*)d_in[10];
    const float* lin2_b  = (const float*)d_in[11];
    float*       out     = (float*)d_out;

    char* wbase = (char*)d_ws;
    size_t off = 0;
    auto alloc = [&](size_t bytes) -> void* {
        off = (off + 255) & ~(size_t)255;
        void* p = wbase + off;
        off += bytes;
        return p;
    };
    int*            degi     = (int*)           alloc((size_t)N_NODES * 4);
    int*            offsets  = (int*)           alloc((size_t)N_NODES * 4);
    int*            cursor   = (int*)           alloc((size_t)N_NODES * 4);
    int*            csr_row  = (int*)           alloc((size_t)ETOT * 4);
    float*          csr_norm = (float*)         alloc((size_t)ETOT * 4);
    float*          XH       = (float*)         alloc((size_t)4 * N_NODES * H_DIM * 4);
    float*          Qb       = (float*)         alloc((size_t)N_NODES * H_DIM * 4);
    unsigned short* Kb       = (unsigned short*)alloc((size_t)N_NODES * 3 * H_DIM * 2);
    unsigned short* Vb       = (unsigned short*)alloc((size_t)N_NODES * 3 * H_DIM * 2);

    // graph preprocessing (shared by all 3 layers)
    k_deg_init <<<(N_NODES + 255) / 256, 256, 0, stream>>>(degi);
    k_deg_count<<<(NEDGES + 255) / 256, 256, 0, stream>>>(col, degi);
    k_scan     <<<1, 256, 0, stream>>>(degi, offsets, cursor);
    k_scatter  <<<(ETOT + 255) / 256, 256, 0, stream>>>(row, col, degi, offsets, cursor,
                                                        csr_row, csr_norm);

    // x0 = relu(x_param @ lin1_w + lin1_b)
    k_gemm<<<TILES_N, 256, 0, stream>>>(x_param, lin1_w, lin1_b, XH, N_NODES, F_IN_D, 1);

    for (int l = 0; l < 3; ++l) {
        int t = l + 1;
        k_qkv<<<(1 + 2 * t) * TILES_N, 256, 0, stream>>>(
            XH,
            wq + (size_t)l * H_DIM * H_DIM, wk + (size_t)l * H_DIM * H_DIM,
            wv + (size_t)l * H_DIM * H_DIM,
            bq + l * H_DIM, bk + l * H_DIM, bv + l * H_DIM,
            Qb, Kb, Vb, l, t, H_DIM);
        float* Xnext = XH + (size_t)(l + 1) * N_NODES * H_DIM;
        if (t == 1)
            k_attn_agg<1><<<N_NODES, 128, 0, stream>>>(Qb, Kb, Vb, csr_row, csr_norm,
                                                       offsets, degi, Xnext);
        else if (t == 2)
            k_attn_agg<2><<<N_NODES, 128, 0, stream>>>(Qb, Kb, Vb, csr_row, csr_norm,
                                                       offsets, degi, Xnext);
        else
            k_attn_agg<3><<<N_NODES, 128, 0, stream>>>(Qb, Kb, Vb, csr_row, csr_norm,
                                                       offsets, degi, Xnext);
    }

    k_lin2<<<(N_NODES + 3) / 4, 256, 0, stream>>>(XH + (size_t)3 * N_NODES * H_DIM,
                                                  lin2_w, lin2_b, out);
}

// Round 9
// 409.437 us; speedup vs baseline: 6.2989x; 1.2989x over previous
//
#include <hip/hip_runtime.h>
#include <math.h>

#define N_NODES 10000
#define F_IN_D  256
#define H_DIM   128
#define C_OUTD  40
#define NHEADS  8
#define NEDGES  160000
#define ETOT    (NEDGES + N_NODES)
#define SCALE_F 0.25f  /* 1/sqrt(16) */
#define TILES_N 157    /* ceil(10000/64) */

typedef __attribute__((ext_vector_type(8))) short bf16x8;   // 8 bf16 = 4 VGPRs
typedef __attribute__((ext_vector_type(4))) float f32x4;

__device__ __forceinline__ unsigned short f2bf(float f) {
    unsigned int u = __float_as_uint(f);
    unsigned int r = (u + 0x7FFFu + ((u >> 16) & 1u)) >> 16;  // RNE
    return (unsigned short)r;
}
__device__ __forceinline__ float bf2f(unsigned short h) {
    return __uint_as_float(((unsigned int)h) << 16);
}

// ---------------- graph preprocessing ----------------

__global__ void k_deg_init(int* degi) {
    int i = blockIdx.x * 256 + threadIdx.x;
    if (i < N_NODES) degi[i] = 1;  // self-loop
}

__global__ void k_deg_count(const int* __restrict__ col, int* degi) {
    int e = blockIdx.x * 256 + threadIdx.x;
    if (e < NEDGES) atomicAdd(&degi[col[e]], 1);
}

__global__ void k_scan(const int* __restrict__ degi, int* offsets, int* cursor) {
    __shared__ int part[256];
    int tid = threadIdx.x;
    int s = 0;
    if (tid < 250) {
        const int4* d4 = (const int4*)degi;
        for (int i = 0; i < 10; ++i) {
            int4 v = d4[tid * 10 + i];
            s += v.x + v.y + v.z + v.w;
        }
    }
    part[tid] = s;
    __syncthreads();
    for (int off = 1; off < 256; off <<= 1) {
        int v = 0;
        if (tid >= off) v = part[tid - off];
        __syncthreads();
        part[tid] += v;
        __syncthreads();
    }
    if (tid < 250) {
        int base = part[tid] - s;  // exclusive prefix
        int beg = tid * 40;
        for (int i = 0; i < 40; ++i) {
            offsets[beg + i] = base;
            cursor[beg + i]  = 0;
            base += degi[beg + i];
        }
    }
}

__global__ void k_scatter(const int* __restrict__ row, const int* __restrict__ col,
                          const int* __restrict__ degi, const int* __restrict__ offsets,
                          int* cursor, int* csr_row, float* csr_norm) {
    int e = blockIdx.x * 256 + threadIdx.x;
    if (e >= ETOT) return;
    int r, c;
    if (e < NEDGES) { r = row[e]; c = col[e]; }
    else            { r = c = e - NEDGES; }   // self-loop
    int slot = offsets[c] + atomicAdd(&cursor[c], 1);
    float dr = rsqrtf((float)degi[r]);
    float dc = rsqrtf((float)degi[c]);
    csr_row[slot]  = r;
    csr_norm[slot] = dr * dc;
}

// ---------------- casts: fp32 -> bf16 (x_param, transposed weights) ----------------

__global__ void k_cast_x(const float* __restrict__ x, unsigned short* __restrict__ xb) {
    int i = blockIdx.x * 256 + threadIdx.x;   // handles 4 elems; grid*4 == 2560000 exactly
    float4 v = *(const float4*)&x[(size_t)i * 4];
    ushort4 o;
    o.x = f2bf(v.x); o.y = f2bf(v.y); o.z = f2bf(v.z); o.w = f2bf(v.w);
    *(ushort4*)&xb[(size_t)i * 4] = o;
}

// W1T[n][k] = lin1_w[k][n] (128x256); WT{q,k,v}[l][n][k] = w{q,k,v}[l][k][n] (3x128x128)
__global__ void k_cast_w(const float* __restrict__ w1, const float* __restrict__ wq,
                         const float* __restrict__ wk, const float* __restrict__ wv,
                         unsigned short* __restrict__ W1T, unsigned short* __restrict__ WTq,
                         unsigned short* __restrict__ WTk, unsigned short* __restrict__ WTv) {
    int e = blockIdx.x * 256 + threadIdx.x;
    if (e < 32768) {
        int n = e >> 8, k = e & 255;
        W1T[e] = f2bf(w1[k * H_DIM + n]);
    } else if (e < 180224) {
        int e2 = e - 32768;
        int mat = e2 >> 14;          // 0..8
        int r   = e2 & 16383;
        int n = r >> 7, k = r & 127;
        int l = mat / 3, ws = mat % 3;
        const float*    src = (ws == 0) ? wq  : (ws == 1) ? wk  : wv;
        unsigned short* dst = (ws == 0) ? WTq : (ws == 1) ? WTk : WTv;
        dst[l * 16384 + n * H_DIM + k] = f2bf(src[l * 16384 + k * H_DIM + n]);
    }
}

// ---------------- MFMA lin1: X0 = relu(x_bf @ W1 + b1), bf16 out ----------------
// LDS-free: A-frags (A[m=lane&15][k=quad*8+j]) and B-frags (WT[n][k]) straight
// from global via uint4. nct is a RUNTIME arg (=8): unknown trip count prevents
// the full-unroll VGPR spill seen in round 3.

__global__ __launch_bounds__(256) void k_lin1_mfma(const unsigned short* __restrict__ Xb,
                                                   const unsigned short* __restrict__ W1T,
                                                   const float* __restrict__ b1,
                                                   unsigned short* __restrict__ X0,
                                                   int nct) {
    int tid = threadIdx.x;
    int wid = tid >> 6, lane = tid & 63;
    int m = lane & 15, quad = lane >> 4;
    int rowA = blockIdx.x * 64 + wid * 16 + m;      // A overread past N_NODES stays in ws
    bf16x8 af[8];
    const unsigned short* ap = Xb + (size_t)rowA * F_IN_D + quad * 8;
    #pragma unroll
    for (int s = 0; s < 8; ++s)
        af[s] = __builtin_bit_cast(bf16x8, *(const uint4*)(ap + s * 32));
    int row0 = blockIdx.x * 64 + wid * 16 + quad * 4;
    for (int ct = 0; ct < nct; ++ct) {
        int col = ct * 16 + m;
        const unsigned short* bp = W1T + (size_t)col * F_IN_D + quad * 8;
        f32x4 acc = {0.f, 0.f, 0.f, 0.f};
        #pragma unroll
        for (int s = 0; s < 8; ++s) {
            bf16x8 bfr = __builtin_bit_cast(bf16x8, *(const uint4*)(bp + s * 32));
            acc = __builtin_amdgcn_mfma_f32_16x16x32_bf16(af[s], bfr, acc, 0, 0, 0);
        }
        float bb = b1[col];
        #pragma unroll
        for (int rg = 0; rg < 4; ++rg) {
            int r = row0 + rg;
            if (r < N_NODES)
                X0[(size_t)r * H_DIM + col] = f2bf(fmaxf(acc[rg] + bb, 0.f));
        }
    }
}

// ---------------- MFMA fused QKV projection ----------------
// grid = (1+2t)*TILES_N; mode 0 = Q (fp32 out), 1..t = K slices, t+1..2t = V.
// K/V layout: [node][slice(3)][128] bf16.

__global__ __launch_bounds__(256) void k_qkv_mfma(const unsigned short* __restrict__ XHb,
                                                  const unsigned short* __restrict__ WTq,
                                                  const unsigned short* __restrict__ WTk,
                                                  const unsigned short* __restrict__ WTv,
                                                  const float* __restrict__ bq,
                                                  const float* __restrict__ bk,
                                                  const float* __restrict__ bv,
                                                  float* __restrict__ Qb,
                                                  unsigned short* __restrict__ Kb,
                                                  unsigned short* __restrict__ Vb,
                                                  int l, int t, int nct) {
    int tid = threadIdx.x;
    int wid = tid >> 6, lane = tid & 63;
    int m = lane & 15, quad = lane >> 4;
    int mi = blockIdx.x / TILES_N;
    int rt = blockIdx.x % TILES_N;
    const unsigned short* WT; const float* bias; int slice, mode;
    if (mi == 0)      { WT = WTq; bias = bq; slice = l;          mode = 0; }
    else if (mi <= t) { WT = WTk; bias = bk; slice = mi - 1;     mode = 1; }
    else              { WT = WTv; bias = bv; slice = mi - t - 1; mode = 2; }
    const unsigned short* A = XHb + (size_t)slice * N_NODES * H_DIM;
    int rowA = rt * 64 + wid * 16 + m;
    bf16x8 af[4];
    const unsigned short* ap = A + (size_t)rowA * H_DIM + quad * 8;
    #pragma unroll
    for (int s = 0; s < 4; ++s)
        af[s] = __builtin_bit_cast(bf16x8, *(const uint4*)(ap + s * 32));
    int row0 = rt * 64 + wid * 16 + quad * 4;
    unsigned short* OutB = (mode == 1) ? Kb : Vb;
    for (int ct = 0; ct < nct; ++ct) {
        int col = ct * 16 + m;
        const unsigned short* bp = WT + (size_t)col * H_DIM + quad * 8;
        f32x4 acc = {0.f, 0.f, 0.f, 0.f};
        #pragma unroll
        for (int s = 0; s < 4; ++s) {
            bf16x8 bfr = __builtin_bit_cast(bf16x8, *(const uint4*)(bp + s * 32));
            acc = __builtin_amdgcn_mfma_f32_16x16x32_bf16(af[s], bfr, acc, 0, 0, 0);
        }
        float bb = bias[col];
        #pragma unroll
        for (int rg = 0; rg < 4; ++rg) {
            int r = row0 + rg;
            if (r < N_NODES) {
                float v = acc[rg] + bb;
                if (mode == 0) Qb[(size_t)r * H_DIM + col] = v;
                else OutB[((size_t)r * 3 + slice) * H_DIM + col] = f2bf(v);
            }
        }
    }
}

// ---------------- fused per-node attention aggregation ----------------
// one block (128 threads = 8 heads x 16 dims) per destination node
// K,V: bf16 [node][slice(3)][128]; output: bf16 X slice

template <int T>
__global__ __launch_bounds__(128) void k_attn_agg(const float* __restrict__ Q,
                                                  const unsigned short* __restrict__ K,
                                                  const unsigned short* __restrict__ V,
                                                  const int* __restrict__ csr_row,
                                                  const float* __restrict__ csr_norm,
                                                  const int* __restrict__ offsets,
                                                  const int* __restrict__ degi,
                                                  unsigned short* __restrict__ Xout) {
    int n = blockIdx.x;
    int tid = threadIdx.x;               // h = tid>>4, d = tid&15
    float qv = Q[(size_t)n * H_DIM + tid] * SCALE_F;
    int start = offsets[n];
    int cnt   = degi[n];
    float acc = 0.f;

    for (int j = 0; j < cnt; ++j) {
        int   r   = csr_row[start + j];
        float nrm = csr_norm[start + j];
        const unsigned short* kp = K + (size_t)r * 3 * H_DIM + tid;
        const unsigned short* vp = V + (size_t)r * 3 * H_DIM + tid;
        float sc[T];
        #pragma unroll
        for (int s = 0; s < T; ++s) {
            float p = qv * bf2f(kp[s * H_DIM]);
            p += __shfl_xor(p, 1, 16);
            p += __shfl_xor(p, 2, 16);
            p += __shfl_xor(p, 4, 16);
            p += __shfl_xor(p, 8, 16);
            sc[s] = p;
        }
        float m = 0.f;
        #pragma unroll
        for (int s = 0; s < T; ++s) m = fmaxf(m, sc[s]);
        float den = expf(-m);            // restricted-softmax null slot
        float mv = 0.f;
        #pragma unroll
        for (int s = 0; s < T; ++s) {
            float wgt = expf(sc[s] - m);
            den += wgt;
            mv  += wgt * bf2f(vp[s * H_DIM]);
        }
        acc += nrm * mv / den;
    }
    Xout[(size_t)n * H_DIM + tid] = f2bf(fmaxf(acc, 0.f));  // relu, bf16
}

// ---------------- fused lin2 + log_softmax (bf16 X in) ----------------

__global__ __launch_bounds__(256) void k_lin2(const unsigned short* __restrict__ X,
                                              const float* __restrict__ W2,
                                              const float* __restrict__ b2,
                                              float* __restrict__ out) {
    int lane = threadIdx.x & 63;
    int n = blockIdx.x * 4 + (threadIdx.x >> 6);
    if (n >= N_NODES) return;            // whole wave exits together
    float acc = (lane < C_OUTD) ? b2[lane] : 0.f;
    for (int k = 0; k < H_DIM; ++k) {
        float xv = bf2f(X[(size_t)n * H_DIM + k]);
        if (lane < C_OUTD) acc += xv * W2[k * C_OUTD + lane];
    }
    float lg = (lane < C_OUTD) ? acc : -INFINITY;
    float m = lg;
    #pragma unroll
    for (int o = 32; o > 0; o >>= 1) m = fmaxf(m, __shfl_xor(m, o, 64));
    float e = (lane < C_OUTD) ? expf(lg - m) : 0.f;
    float ssum = e;
    #pragma unroll
    for (int o = 32; o > 0; o >>= 1) ssum += __shfl_xor(ssum, o, 64);
    float lse = m + logf(ssum);
    if (lane < C_OUTD) out[(size_t)n * C_OUTD + lane] = lg - lse;
}

// ---------------- launcher ----------------

extern "C" void kernel_launch(void* const* d_in, const int* in_sizes, int n_in,
                              void* d_out, int out_size, void* d_ws, size_t ws_size,
                              hipStream_t stream) {
    const int*   ei      = (const int*)d_in[0];
    const int*   row     = ei;
    const int*   col     = ei + NEDGES;
    const float* x_param = (const float*)d_in[1];
    const float* lin1_w  = (const float*)d_in[2];
    const float* lin1_b  = (const float*)d_in[3];
    const float* wq      = (const float*)d_in[4];
    const float* wk      = (const float*)d_in[5];
    const float* wv      = (const float*)d_in[6];
    const float* bq      = (const float*)d_in[7];
    const float* bk      = (const float*)d_in[8];
    const float* bv      = (const float*)d_in[9];
    const float* lin2_w  = (const float*)d_in[10];
    const float* lin2_b  = (const float*)d_in[11];
    float*       out     = (float*)d_out;

    char* wbase = (char*)d_ws;
    size_t off = 0;
    auto alloc = [&](size_t bytes) -> void* {
        off = (off + 255) & ~(size_t)255;
        void* p = wbase + off;
        off += bytes;
        return p;
    };
    int*            degi     = (int*)           alloc((size_t)N_NODES * 4);
    int*            offsets  = (int*)           alloc((size_t)N_NODES * 4);
    int*            cursor   = (int*)           alloc((size_t)N_NODES * 4);
    int*            csr_row  = (int*)           alloc((size_t)ETOT * 4);
    float*          csr_norm = (float*)         alloc((size_t)ETOT * 4);
    unsigned short* xpb      = (unsigned short*)alloc((size_t)N_NODES * F_IN_D * 2);
    unsigned short* W1T      = (unsigned short*)alloc((size_t)H_DIM * F_IN_D * 2);
    unsigned short* WTq      = (unsigned short*)alloc((size_t)3 * H_DIM * H_DIM * 2);
    unsigned short* WTk      = (unsigned short*)alloc((size_t)3 * H_DIM * H_DIM * 2);
    unsigned short* WTv      = (unsigned short*)alloc((size_t)3 * H_DIM * H_DIM * 2);
    unsigned short* XHb      = (unsigned short*)alloc((size_t)4 * N_NODES * H_DIM * 2);
    float*          Qb       = (float*)         alloc((size_t)N_NODES * H_DIM * 4);
    unsigned short* Kb       = (unsigned short*)alloc((size_t)N_NODES * 3 * H_DIM * 2);
    unsigned short* Vb       = (unsigned short*)alloc((size_t)N_NODES * 3 * H_DIM * 2);

    // graph preprocessing (shared by all 3 layers)
    k_deg_init <<<(N_NODES + 255) / 256, 256, 0, stream>>>(degi);
    k_deg_count<<<(NEDGES + 255) / 256, 256, 0, stream>>>(col, degi);
    k_scan     <<<1, 256, 0, stream>>>(degi, offsets, cursor);
    k_scatter  <<<(ETOT + 255) / 256, 256, 0, stream>>>(row, col, degi, offsets, cursor,
                                                        csr_row, csr_norm);

    // bf16 casts
    k_cast_x<<<2500, 256, 0, stream>>>(x_param, xpb);
    k_cast_w<<<704, 256, 0, stream>>>(lin1_w, wq, wk, wv, W1T, WTq, WTk, WTv);

    // x0 = relu(x @ W1 + b1)  [MFMA, bf16 out]
    k_lin1_mfma<<<TILES_N, 256, 0, stream>>>(xpb, W1T, lin1_b, XHb, 8);

    for (int l = 0; l < 3; ++l) {
        int t = l + 1;
        k_qkv_mfma<<<(1 + 2 * t) * TILES_N, 256, 0, stream>>>(
            XHb, WTq + (size_t)l * 16384, WTk + (size_t)l * 16384, WTv + (size_t)l * 16384,
            bq + l * H_DIM, bk + l * H_DIM, bv + l * H_DIM,
            Qb, Kb, Vb, l, t, 8);
        unsigned short* Xnext = XHb + (size_t)(l + 1) * N_NODES * H_DIM;
        if (t == 1)
            k_attn_agg<1><<<N_NODES, 128, 0, stream>>>(Qb, Kb, Vb, csr_row, csr_norm,
                                                       offsets, degi, Xnext);
        else if (t == 2)
            k_attn_agg<2><<<N_NODES, 128, 0, stream>>>(Qb, Kb, Vb, csr_row, csr_norm,
                                                       offsets, degi, Xnext);
        else
            k_attn_agg<3><<<N_NODES, 128, 0, stream>>>(Qb, Kb, Vb, csr_row, csr_norm,
                                                       offsets, degi, Xnext);
    }

    k_lin2<<<(N_NODES + 3) / 4, 256, 0, stream>>>(XHb + (size_t)3 * N_NODES * H_DIM,
                                                  lin2_w, lin2_b, out);
}

// Round 10
// 351.348 us; speedup vs baseline: 7.3403x; 1.1653x over previous
//
#include <hip/hip_runtime.h>
#include <math.h>

#define N_NODES 10000
#define F_IN_D  256
#define H_DIM   128
#define C_OUTD  40
#define NHEADS  8
#define NEDGES  160000
#define ETOT    (NEDGES + N_NODES)
#define SCALE_F 0.25f  /* 1/sqrt(16) */
#define TILES_N 157    /* ceil(10000/64) */

typedef __attribute__((ext_vector_type(8))) short bf16x8;   // 8 bf16 = 4 VGPRs
typedef __attribute__((ext_vector_type(4))) float f32x4;

__device__ __forceinline__ unsigned short f2bf(float f) {
    unsigned int u = __float_as_uint(f);
    unsigned int r = (u + 0x7FFFu + ((u >> 16) & 1u)) >> 16;  // RNE
    return (unsigned short)r;
}
__device__ __forceinline__ float bf2f(unsigned short h) {
    return __uint_as_float(((unsigned int)h) << 16);
}

// ---------------- graph preprocessing ----------------

__global__ void k_deg_init(int* degi) {
    int i = blockIdx.x * 256 + threadIdx.x;
    if (i < N_NODES) degi[i] = 1;  // self-loop
}

__global__ void k_deg_count(const int* __restrict__ col, int* degi) {
    int e = blockIdx.x * 256 + threadIdx.x;
    if (e < NEDGES) atomicAdd(&degi[col[e]], 1);
}

__global__ void k_scan(const int* __restrict__ degi, int* offsets, int* cursor) {
    __shared__ int part[256];
    int tid = threadIdx.x;
    int s = 0;
    if (tid < 250) {
        const int4* d4 = (const int4*)degi;
        for (int i = 0; i < 10; ++i) {
            int4 v = d4[tid * 10 + i];
            s += v.x + v.y + v.z + v.w;
        }
    }
    part[tid] = s;
    __syncthreads();
    for (int off = 1; off < 256; off <<= 1) {
        int v = 0;
        if (tid >= off) v = part[tid - off];
        __syncthreads();
        part[tid] += v;
        __syncthreads();
    }
    if (tid < 250) {
        int base = part[tid] - s;  // exclusive prefix
        int beg = tid * 40;
        for (int i = 0; i < 40; ++i) {
            offsets[beg + i] = base;
            cursor[beg + i]  = 0;
            base += degi[beg + i];
        }
    }
}

__global__ void k_scatter(const int* __restrict__ row, const int* __restrict__ col,
                          const int* __restrict__ degi, const int* __restrict__ offsets,
                          int* cursor, int* csr_row, float* csr_norm) {
    int e = blockIdx.x * 256 + threadIdx.x;
    if (e >= ETOT) return;
    int r, c;
    if (e < NEDGES) { r = row[e]; c = col[e]; }
    else            { r = c = e - NEDGES; }   // self-loop
    int slot = offsets[c] + atomicAdd(&cursor[c], 1);
    float dr = rsqrtf((float)degi[r]);
    float dc = rsqrtf((float)degi[c]);
    csr_row[slot]  = r;
    csr_norm[slot] = dr * dc;
}

// ---------------- casts: fp32 -> bf16 (x_param, transposed weights) ----------------

__global__ void k_cast_x(const float* __restrict__ x, unsigned short* __restrict__ xb) {
    int i = blockIdx.x * 256 + threadIdx.x;   // handles 4 elems; grid*4 == 2560000 exactly
    float4 v = *(const float4*)&x[(size_t)i * 4];
    ushort4 o;
    o.x = f2bf(v.x); o.y = f2bf(v.y); o.z = f2bf(v.z); o.w = f2bf(v.w);
    *(ushort4*)&xb[(size_t)i * 4] = o;
}

// W1T[n][k] = lin1_w[k][n] (128x256); WT{q,k,v}[l][n][k] = w{q,k,v}[l][k][n] (3x128x128)
__global__ void k_cast_w(const float* __restrict__ w1, const float* __restrict__ wq,
                         const float* __restrict__ wk, const float* __restrict__ wv,
                         unsigned short* __restrict__ W1T, unsigned short* __restrict__ WTq,
                         unsigned short* __restrict__ WTk, unsigned short* __restrict__ WTv) {
    int e = blockIdx.x * 256 + threadIdx.x;
    if (e < 32768) {
        int n = e >> 8, k = e & 255;
        W1T[e] = f2bf(w1[k * H_DIM + n]);
    } else if (e < 180224) {
        int e2 = e - 32768;
        int mat = e2 >> 14;          // 0..8
        int r   = e2 & 16383;
        int n = r >> 7, k = r & 127;
        int l = mat / 3, ws = mat % 3;
        const float*    src = (ws == 0) ? wq  : (ws == 1) ? wk  : wv;
        unsigned short* dst = (ws == 0) ? WTq : (ws == 1) ? WTk : WTv;
        dst[l * 16384 + n * H_DIM + k] = f2bf(src[l * 16384 + k * H_DIM + n]);
    }
}

// ---------------- MFMA lin1: X0 = relu(x_bf @ W1 + b1), bf16 out ----------------
// LDS-free: A-frags (A[m=lane&15][k=quad*8+j]) and B-frags (WT[n][k]) straight
// from global via uint4. nct is a RUNTIME arg (=8): unknown trip count prevents
// the full-unroll VGPR spill seen in round 3.

__global__ __launch_bounds__(256) void k_lin1_mfma(const unsigned short* __restrict__ Xb,
                                                   const unsigned short* __restrict__ W1T,
                                                   const float* __restrict__ b1,
                                                   unsigned short* __restrict__ X0,
                                                   int nct) {
    int tid = threadIdx.x;
    int wid = tid >> 6, lane = tid & 63;
    int m = lane & 15, quad = lane >> 4;
    int rowA = blockIdx.x * 64 + wid * 16 + m;      // A overread past N_NODES stays in ws
    bf16x8 af[8];
    const unsigned short* ap = Xb + (size_t)rowA * F_IN_D + quad * 8;
    #pragma unroll
    for (int s = 0; s < 8; ++s)
        af[s] = __builtin_bit_cast(bf16x8, *(const uint4*)(ap + s * 32));
    int row0 = blockIdx.x * 64 + wid * 16 + quad * 4;
    for (int ct = 0; ct < nct; ++ct) {
        int col = ct * 16 + m;
        const unsigned short* bp = W1T + (size_t)col * F_IN_D + quad * 8;
        f32x4 acc = {0.f, 0.f, 0.f, 0.f};
        #pragma unroll
        for (int s = 0; s < 8; ++s) {
            bf16x8 bfr = __builtin_bit_cast(bf16x8, *(const uint4*)(bp + s * 32));
            acc = __builtin_amdgcn_mfma_f32_16x16x32_bf16(af[s], bfr, acc, 0, 0, 0);
        }
        float bb = b1[col];
        #pragma unroll
        for (int rg = 0; rg < 4; ++rg) {
            int r = row0 + rg;
            if (r < N_NODES)
                X0[(size_t)r * H_DIM + col] = f2bf(fmaxf(acc[rg] + bb, 0.f));
        }
    }
}

// ---------------- MFMA fused QKV projection ----------------
// grid = (1+2t)*TILES_N; mode 0 = Q (fp32 out), 1..t = K slices, t+1..2t = V.
// K/V layout: [node][slice(3)][128] bf16.

__global__ __launch_bounds__(256) void k_qkv_mfma(const unsigned short* __restrict__ XHb,
                                                  const unsigned short* __restrict__ WTq,
                                                  const unsigned short* __restrict__ WTk,
                                                  const unsigned short* __restrict__ WTv,
                                                  const float* __restrict__ bq,
                                                  const float* __restrict__ bk,
                                                  const float* __restrict__ bv,
                                                  float* __restrict__ Qb,
                                                  unsigned short* __restrict__ Kb,
                                                  unsigned short* __restrict__ Vb,
                                                  int l, int t, int nct) {
    int tid = threadIdx.x;
    int wid = tid >> 6, lane = tid & 63;
    int m = lane & 15, quad = lane >> 4;
    int mi = blockIdx.x / TILES_N;
    int rt = blockIdx.x % TILES_N;
    const unsigned short* WT; const float* bias; int slice, mode;
    if (mi == 0)      { WT = WTq; bias = bq; slice = l;          mode = 0; }
    else if (mi <= t) { WT = WTk; bias = bk; slice = mi - 1;     mode = 1; }
    else              { WT = WTv; bias = bv; slice = mi - t - 1; mode = 2; }
    const unsigned short* A = XHb + (size_t)slice * N_NODES * H_DIM;
    int rowA = rt * 64 + wid * 16 + m;
    bf16x8 af[4];
    const unsigned short* ap = A + (size_t)rowA * H_DIM + quad * 8;
    #pragma unroll
    for (int s = 0; s < 4; ++s)
        af[s] = __builtin_bit_cast(bf16x8, *(const uint4*)(ap + s * 32));
    int row0 = rt * 64 + wid * 16 + quad * 4;
    unsigned short* OutB = (mode == 1) ? Kb : Vb;
    for (int ct = 0; ct < nct; ++ct) {
        int col = ct * 16 + m;
        const unsigned short* bp = WT + (size_t)col * H_DIM + quad * 8;
        f32x4 acc = {0.f, 0.f, 0.f, 0.f};
        #pragma unroll
        for (int s = 0; s < 4; ++s) {
            bf16x8 bfr = __builtin_bit_cast(bf16x8, *(const uint4*)(bp + s * 32));
            acc = __builtin_amdgcn_mfma_f32_16x16x32_bf16(af[s], bfr, acc, 0, 0, 0);
        }
        float bb = bias[col];
        #pragma unroll
        for (int rg = 0; rg < 4; ++rg) {
            int r = row0 + rg;
            if (r < N_NODES) {
                float v = acc[rg] + bb;
                if (mode == 0) Qb[(size_t)r * H_DIM + col] = v;
                else OutB[((size_t)r * 3 + slice) * H_DIM + col] = f2bf(v);
            }
        }
    }
}

// ---------------- fused per-node attention aggregation (wave-per-node) ----------------
// 256 threads = 4 waves = 4 nodes; lane: h = lane>>3 (8 heads), dp = lane&7
// (2 dims per lane, packed bf16 pair in one uint). K,V viewed as uint
// [node][slice(3)][64]. 3-step width-8 shfl reduction; free bf16->fp32 via
// bit ops; __expf / __fdividef fast paths.

template <int T>
__global__ __launch_bounds__(256) void k_attn_agg(const float* __restrict__ Q,
                                                  const unsigned int* __restrict__ K,
                                                  const unsigned int* __restrict__ V,
                                                  const int* __restrict__ csr_row,
                                                  const float* __restrict__ csr_norm,
                                                  const int* __restrict__ offsets,
                                                  const int* __restrict__ degi,
                                                  unsigned int* __restrict__ Xout) {
    int tid = threadIdx.x;
    int wid = tid >> 6, lane = tid & 63;
    int n = blockIdx.x * 4 + wid;        // grid 2500*4 == N_NODES exactly
    int ci = lane;                        // h*8+dp, uint index within 64
    float2 q2 = *(const float2*)&Q[(size_t)n * H_DIM + ci * 2];
    float q0 = q2.x * SCALE_F, q1 = q2.y * SCALE_F;
    int start = offsets[n];
    int cnt   = degi[n];
    float acc0 = 0.f, acc1 = 0.f;

    for (int j = 0; j < cnt; ++j) {
        int idx = __builtin_amdgcn_readfirstlane(start + j);  // wave-uniform -> s_load
        int   r   = csr_row[idx];
        float nrm = csr_norm[idx];
        const unsigned int* kp = K + (size_t)r * 192 + ci;
        const unsigned int* vp = V + (size_t)r * 192 + ci;
        unsigned int kw[T], vw[T];
        #pragma unroll
        for (int s = 0; s < T; ++s) { kw[s] = kp[s * 64]; vw[s] = vp[s * 64]; }
        float sc[T];
        #pragma unroll
        for (int s = 0; s < T; ++s) {
            float p = q0 * __uint_as_float(kw[s] << 16)
                    + q1 * __uint_as_float(kw[s] & 0xffff0000u);
            p += __shfl_xor(p, 1, 8);
            p += __shfl_xor(p, 2, 8);
            p += __shfl_xor(p, 4, 8);
            sc[s] = p;                   // all 8 lanes of the head hold the dot
        }
        float m = 0.f;
        #pragma unroll
        for (int s = 0; s < T; ++s) m = fmaxf(m, sc[s]);
        float den = __expf(-m);          // restricted-softmax null slot
        float mv0 = 0.f, mv1 = 0.f;
        #pragma unroll
        for (int s = 0; s < T; ++s) {
            float w = __expf(sc[s] - m);
            den += w;
            mv0 += w * __uint_as_float(vw[s] << 16);
            mv1 += w * __uint_as_float(vw[s] & 0xffff0000u);
        }
        float ws = __fdividef(nrm, den);
        acc0 += ws * mv0;
        acc1 += ws * mv1;
    }
    unsigned int o = ((unsigned int)f2bf(fmaxf(acc1, 0.f)) << 16)
                   |  (unsigned int)f2bf(fmaxf(acc0, 0.f));   // relu, packed bf16
    Xout[(size_t)n * 64 + ci] = o;
}

// ---------------- fused lin2 + log_softmax (bf16 X in) ----------------

__global__ __launch_bounds__(256) void k_lin2(const unsigned short* __restrict__ X,
                                              const float* __restrict__ W2,
                                              const float* __restrict__ b2,
                                              float* __restrict__ out) {
    int lane = threadIdx.x & 63;
    int n = blockIdx.x * 4 + (threadIdx.x >> 6);
    if (n >= N_NODES) return;            // whole wave exits together
    float acc = (lane < C_OUTD) ? b2[lane] : 0.f;
    for (int k = 0; k < H_DIM; ++k) {
        float xv = bf2f(X[(size_t)n * H_DIM + k]);
        if (lane < C_OUTD) acc += xv * W2[k * C_OUTD + lane];
    }
    float lg = (lane < C_OUTD) ? acc : -INFINITY;
    float m = lg;
    #pragma unroll
    for (int o = 32; o > 0; o >>= 1) m = fmaxf(m, __shfl_xor(m, o, 64));
    float e = (lane < C_OUTD) ? expf(lg - m) : 0.f;
    float ssum = e;
    #pragma unroll
    for (int o = 32; o > 0; o >>= 1) ssum += __shfl_xor(ssum, o, 64);
    float lse = m + logf(ssum);
    if (lane < C_OUTD) out[(size_t)n * C_OUTD + lane] = lg - lse;
}

// ---------------- launcher ----------------

extern "C" void kernel_launch(void* const* d_in, const int* in_sizes, int n_in,
                              void* d_out, int out_size, void* d_ws, size_t ws_size,
                              hipStream_t stream) {
    const int*   ei      = (const int*)d_in[0];
    const int*   row     = ei;
    const int*   col     = ei + NEDGES;
    const float* x_param = (const float*)d_in[1];
    const float* lin1_w  = (const float*)d_in[2];
    const float* lin1_b  = (const float*)d_in[3];
    const float* wq      = (const float*)d_in[4];
    const float* wk      = (const float*)d_in[5];
    const float* wv      = (const float*)d_in[6];
    const float* bq      = (const float*)d_in[7];
    const float* bk      = (const float*)d_in[8];
    const float* bv      = (const float*)d_in[9];
    const float* lin2_w  = (const float*)d_in[10];
    const float* lin2_b  = (const float*)d_in[11];
    float*       out     = (float*)d_out;

    char* wbase = (char*)d_ws;
    size_t off = 0;
    auto alloc = [&](size_t bytes) -> void* {
        off = (off + 255) & ~(size_t)255;
        void* p = wbase + off;
        off += bytes;
        return p;
    };
    int*            degi     = (int*)           alloc((size_t)N_NODES * 4);
    int*            offsets  = (int*)           alloc((size_t)N_NODES * 4);
    int*            cursor   = (int*)           alloc((size_t)N_NODES * 4);
    int*            csr_row  = (int*)           alloc((size_t)ETOT * 4);
    float*          csr_norm = (float*)         alloc((size_t)ETOT * 4);
    unsigned short* xpb      = (unsigned short*)alloc((size_t)N_NODES * F_IN_D * 2);
    unsigned short* W1T      = (unsigned short*)alloc((size_t)H_DIM * F_IN_D * 2);
    unsigned short* WTq      = (unsigned short*)alloc((size_t)3 * H_DIM * H_DIM * 2);
    unsigned short* WTk      = (unsigned short*)alloc((size_t)3 * H_DIM * H_DIM * 2);
    unsigned short* WTv      = (unsigned short*)alloc((size_t)3 * H_DIM * H_DIM * 2);
    unsigned short* XHb      = (unsigned short*)alloc((size_t)4 * N_NODES * H_DIM * 2);
    float*          Qb       = (float*)         alloc((size_t)N_NODES * H_DIM * 4);
    unsigned short* Kb       = (unsigned short*)alloc((size_t)N_NODES * 3 * H_DIM * 2);
    unsigned short* Vb       = (unsigned short*)alloc((size_t)N_NODES * 3 * H_DIM * 2);

    // graph preprocessing (shared by all 3 layers)
    k_deg_init <<<(N_NODES + 255) / 256, 256, 0, stream>>>(degi);
    k_deg_count<<<(NEDGES + 255) / 256, 256, 0, stream>>>(col, degi);
    k_scan     <<<1, 256, 0, stream>>>(degi, offsets, cursor);
    k_scatter  <<<(ETOT + 255) / 256, 256, 0, stream>>>(row, col, degi, offsets, cursor,
                                                        csr_row, csr_norm);

    // bf16 casts
    k_cast_x<<<2500, 256, 0, stream>>>(x_param, xpb);
    k_cast_w<<<704, 256, 0, stream>>>(lin1_w, wq, wk, wv, W1T, WTq, WTk, WTv);

    // x0 = relu(x @ W1 + b1)  [MFMA, bf16 out]
    k_lin1_mfma<<<TILES_N, 256, 0, stream>>>(xpb, W1T, lin1_b, XHb, 8);

    for (int l = 0; l < 3; ++l) {
        int t = l + 1;
        k_qkv_mfma<<<(1 + 2 * t) * TILES_N, 256, 0, stream>>>(
            XHb, WTq + (size_t)l * 16384, WTk + (size_t)l * 16384, WTv + (size_t)l * 16384,
            bq + l * H_DIM, bk + l * H_DIM, bv + l * H_DIM,
            Qb, Kb, Vb, l, t, 8);
        unsigned int* Xnext = (unsigned int*)(XHb + (size_t)(l + 1) * N_NODES * H_DIM);
        if (t == 1)
            k_attn_agg<1><<<2500, 256, 0, stream>>>(Qb, (const unsigned int*)Kb,
                                                    (const unsigned int*)Vb, csr_row,
                                                    csr_norm, offsets, degi, Xnext);
        else if (t == 2)
            k_attn_agg<2><<<2500, 256, 0, stream>>>(Qb, (const unsigned int*)Kb,
                                                    (const unsigned int*)Vb, csr_row,
                                                    csr_norm, offsets, degi, Xnext);
        else
            k_attn_agg<3><<<2500, 256, 0, stream>>>(Qb, (const unsigned int*)Kb,
                                                    (const unsigned int*)Vb, csr_row,
                                                    csr_norm, offsets, degi, Xnext);
    }

    k_lin2<<<(N_NODES + 3) / 4, 256, 0, stream>>>(XHb + (size_t)3 * N_NODES * H_DIM,
                                                  lin2_w, lin2_b, out);
}

// Round 11
// 311.823 us; speedup vs baseline: 8.2707x; 1.1268x over previous
//
#include <hip/hip_runtime.h>
#include <math.h>

#define N_NODES 10000
#define F_IN_D  256
#define H_DIM   128
#define C_OUTD  40
#define NHEADS  8
#define NEDGES  160000
#define ETOT    (NEDGES + N_NODES)
#define SCALE_F 0.25f  /* 1/sqrt(16) */
#define TILES_N 157    /* ceil(10000/64) */

typedef __attribute__((ext_vector_type(8))) short bf16x8;   // 8 bf16 = 4 VGPRs
typedef __attribute__((ext_vector_type(4))) float f32x4;

__device__ __forceinline__ unsigned short f2bf(float f) {
    unsigned int u = __float_as_uint(f);
    unsigned int r = (u + 0x7FFFu + ((u >> 16) & 1u)) >> 16;  // RNE
    return (unsigned short)r;
}
__device__ __forceinline__ float bf2f(unsigned short h) {
    return __uint_as_float(((unsigned int)h) << 16);
}

// ---------------- graph preprocessing ----------------

__global__ void k_deg_init(int* degi) {
    int i = blockIdx.x * 256 + threadIdx.x;
    if (i < N_NODES) degi[i] = 1;  // self-loop
}

__global__ void k_deg_count(const int* __restrict__ col, int* degi) {
    int e = blockIdx.x * 256 + threadIdx.x;
    if (e < NEDGES) atomicAdd(&degi[col[e]], 1);
}

__global__ void k_scan(const int* __restrict__ degi, int* offsets, int* cursor) {
    __shared__ int part[256];
    int tid = threadIdx.x;
    int s = 0;
    if (tid < 250) {
        const int4* d4 = (const int4*)degi;
        for (int i = 0; i < 10; ++i) {
            int4 v = d4[tid * 10 + i];
            s += v.x + v.y + v.z + v.w;
        }
    }
    part[tid] = s;
    __syncthreads();
    for (int off = 1; off < 256; off <<= 1) {
        int v = 0;
        if (tid >= off) v = part[tid - off];
        __syncthreads();
        part[tid] += v;
        __syncthreads();
    }
    if (tid < 250) {
        int base = part[tid] - s;  // exclusive prefix
        int beg = tid * 40;
        for (int i = 0; i < 40; ++i) {
            offsets[beg + i] = base;
            cursor[beg + i]  = 0;
            base += degi[beg + i];
        }
    }
}

__global__ void k_scatter(const int* __restrict__ row, const int* __restrict__ col,
                          const int* __restrict__ degi, const int* __restrict__ offsets,
                          int* cursor, int* csr_row, float* csr_norm) {
    int e = blockIdx.x * 256 + threadIdx.x;
    if (e >= ETOT) return;
    int r, c;
    if (e < NEDGES) { r = row[e]; c = col[e]; }
    else            { r = c = e - NEDGES; }   // self-loop
    int slot = offsets[c] + atomicAdd(&cursor[c], 1);
    float dr = rsqrtf((float)degi[r]);
    float dc = rsqrtf((float)degi[c]);
    csr_row[slot]  = r;
    csr_norm[slot] = dr * dc;
}

// ---------------- casts: fp32 -> bf16 (x_param, transposed weights) ----------------

__global__ void k_cast_x(const float* __restrict__ x, unsigned short* __restrict__ xb) {
    int i = blockIdx.x * 256 + threadIdx.x;   // handles 4 elems; grid*4 == 2560000 exactly
    float4 v = *(const float4*)&x[(size_t)i * 4];
    ushort4 o;
    o.x = f2bf(v.x); o.y = f2bf(v.y); o.z = f2bf(v.z); o.w = f2bf(v.w);
    *(ushort4*)&xb[(size_t)i * 4] = o;
}

// W1T[n][k] = lin1_w[k][n] (128x256); WT{q,k,v}[l][n][k] = w{q,k,v}[l][k][n] (3x128x128)
// W2T[c][k] = lin2_w[k][c] (48x128, cols 40..47 zero-padded)
__global__ void k_cast_w(const float* __restrict__ w1, const float* __restrict__ wq,
                         const float* __restrict__ wk, const float* __restrict__ wv,
                         const float* __restrict__ w2,
                         unsigned short* __restrict__ W1T, unsigned short* __restrict__ WTq,
                         unsigned short* __restrict__ WTk, unsigned short* __restrict__ WTv,
                         unsigned short* __restrict__ W2T) {
    int e = blockIdx.x * 256 + threadIdx.x;
    if (e < 32768) {
        int n = e >> 8, k = e & 255;
        W1T[e] = f2bf(w1[k * H_DIM + n]);
    } else if (e < 180224) {
        int e2 = e - 32768;
        int mat = e2 >> 14;          // 0..8
        int r   = e2 & 16383;
        int n = r >> 7, k = r & 127;
        int l = mat / 3, ws = mat % 3;
        const float*    src = (ws == 0) ? wq  : (ws == 1) ? wk  : wv;
        unsigned short* dst = (ws == 0) ? WTq : (ws == 1) ? WTk : WTv;
        dst[l * 16384 + n * H_DIM + k] = f2bf(src[l * 16384 + k * H_DIM + n]);
    } else if (e < 186368) {
        int e3 = e - 180224;
        int c = e3 >> 7, k = e3 & 127;
        W2T[c * H_DIM + k] = (c < C_OUTD) ? f2bf(w2[k * C_OUTD + c]) : 0;
    }
}

// ---------------- MFMA lin1: X0 = relu(x_bf @ W1 + b1), bf16 out ----------------
// LDS-free: A-frags (A[m=lane&15][k=quad*8+j]) and B-frags (WT[n][k]) straight
// from global via uint4. nct is a RUNTIME arg (=8): unknown trip count prevents
// the full-unroll VGPR spill seen in round 3.

__global__ __launch_bounds__(256) void k_lin1_mfma(const unsigned short* __restrict__ Xb,
                                                   const unsigned short* __restrict__ W1T,
                                                   const float* __restrict__ b1,
                                                   unsigned short* __restrict__ X0,
                                                   int nct) {
    int tid = threadIdx.x;
    int wid = tid >> 6, lane = tid & 63;
    int m = lane & 15, quad = lane >> 4;
    int rowA = blockIdx.x * 64 + wid * 16 + m;      // A overread past N_NODES stays in ws
    bf16x8 af[8];
    const unsigned short* ap = Xb + (size_t)rowA * F_IN_D + quad * 8;
    #pragma unroll
    for (int s = 0; s < 8; ++s)
        af[s] = __builtin_bit_cast(bf16x8, *(const uint4*)(ap + s * 32));
    int row0 = blockIdx.x * 64 + wid * 16 + quad * 4;
    for (int ct = 0; ct < nct; ++ct) {
        int col = ct * 16 + m;
        const unsigned short* bp = W1T + (size_t)col * F_IN_D + quad * 8;
        f32x4 acc = {0.f, 0.f, 0.f, 0.f};
        #pragma unroll
        for (int s = 0; s < 8; ++s) {
            bf16x8 bfr = __builtin_bit_cast(bf16x8, *(const uint4*)(bp + s * 32));
            acc = __builtin_amdgcn_mfma_f32_16x16x32_bf16(af[s], bfr, acc, 0, 0, 0);
        }
        float bb = b1[col];
        #pragma unroll
        for (int rg = 0; rg < 4; ++rg) {
            int r = row0 + rg;
            if (r < N_NODES)
                X0[(size_t)r * H_DIM + col] = f2bf(fmaxf(acc[rg] + bb, 0.f));
        }
    }
}

// ---------------- MFMA fused QKV projection ----------------
// grid = (1+2t)*TILES_N; mode 0 = Q (fp32 out), 1..t = K slices, t+1..2t = V.
// K/V layout: [node][slice(3)][128] bf16.

__global__ __launch_bounds__(256) void k_qkv_mfma(const unsigned short* __restrict__ XHb,
                                                  const unsigned short* __restrict__ WTq,
                                                  const unsigned short* __restrict__ WTk,
                                                  const unsigned short* __restrict__ WTv,
                                                  const float* __restrict__ bq,
                                                  const float* __restrict__ bk,
                                                  const float* __restrict__ bv,
                                                  float* __restrict__ Qb,
                                                  unsigned short* __restrict__ Kb,
                                                  unsigned short* __restrict__ Vb,
                                                  int l, int t, int nct) {
    int tid = threadIdx.x;
    int wid = tid >> 6, lane = tid & 63;
    int m = lane & 15, quad = lane >> 4;
    int mi = blockIdx.x / TILES_N;
    int rt = blockIdx.x % TILES_N;
    const unsigned short* WT; const float* bias; int slice, mode;
    if (mi == 0)      { WT = WTq; bias = bq; slice = l;          mode = 0; }
    else if (mi <= t) { WT = WTk; bias = bk; slice = mi - 1;     mode = 1; }
    else              { WT = WTv; bias = bv; slice = mi - t - 1; mode = 2; }
    const unsigned short* A = XHb + (size_t)slice * N_NODES * H_DIM;
    int rowA = rt * 64 + wid * 16 + m;
    bf16x8 af[4];
    const unsigned short* ap = A + (size_t)rowA * H_DIM + quad * 8;
    #pragma unroll
    for (int s = 0; s < 4; ++s)
        af[s] = __builtin_bit_cast(bf16x8, *(const uint4*)(ap + s * 32));
    int row0 = rt * 64 + wid * 16 + quad * 4;
    unsigned short* OutB = (mode == 1) ? Kb : Vb;
    for (int ct = 0; ct < nct; ++ct) {
        int col = ct * 16 + m;
        const unsigned short* bp = WT + (size_t)col * H_DIM + quad * 8;
        f32x4 acc = {0.f, 0.f, 0.f, 0.f};
        #pragma unroll
        for (int s = 0; s < 4; ++s) {
            bf16x8 bfr = __builtin_bit_cast(bf16x8, *(const uint4*)(bp + s * 32));
            acc = __builtin_amdgcn_mfma_f32_16x16x32_bf16(af[s], bfr, acc, 0, 0, 0);
        }
        float bb = bias[col];
        #pragma unroll
        for (int rg = 0; rg < 4; ++rg) {
            int r = row0 + rg;
            if (r < N_NODES) {
                float v = acc[rg] + bb;
                if (mode == 0) Qb[(size_t)r * H_DIM + col] = v;
                else OutB[((size_t)r * 3 + slice) * H_DIM + col] = f2bf(v);
            }
        }
    }
}

// ---------------- fused per-node attention aggregation (wave-per-node) ----------------
// 256 threads = 4 waves = 4 nodes; lane: h = lane>>3 (8 heads), dp = lane&7
// (2 dims per lane, packed bf16 pair in one uint). K,V viewed as uint
// [node][slice(3)][64].

template <int T>
__global__ __launch_bounds__(256) void k_attn_agg(const float* __restrict__ Q,
                                                  const unsigned int* __restrict__ K,
                                                  const unsigned int* __restrict__ V,
                                                  const int* __restrict__ csr_row,
                                                  const float* __restrict__ csr_norm,
                                                  const int* __restrict__ offsets,
                                                  const int* __restrict__ degi,
                                                  unsigned int* __restrict__ Xout) {
    int tid = threadIdx.x;
    int wid = tid >> 6, lane = tid & 63;
    int n = blockIdx.x * 4 + wid;        // grid 2500*4 == N_NODES exactly
    int ci = lane;                        // h*8+dp, uint index within 64
    float2 q2 = *(const float2*)&Q[(size_t)n * H_DIM + ci * 2];
    float q0 = q2.x * SCALE_F, q1 = q2.y * SCALE_F;
    int start = offsets[n];
    int cnt   = degi[n];
    float acc0 = 0.f, acc1 = 0.f;

    for (int j = 0; j < cnt; ++j) {
        int idx = __builtin_amdgcn_readfirstlane(start + j);  // wave-uniform -> s_load
        int   r   = csr_row[idx];
        float nrm = csr_norm[idx];
        const unsigned int* kp = K + (size_t)r * 192 + ci;
        const unsigned int* vp = V + (size_t)r * 192 + ci;
        unsigned int kw[T], vw[T];
        #pragma unroll
        for (int s = 0; s < T; ++s) { kw[s] = kp[s * 64]; vw[s] = vp[s * 64]; }
        float sc[T];
        #pragma unroll
        for (int s = 0; s < T; ++s) {
            float p = q0 * __uint_as_float(kw[s] << 16)
                    + q1 * __uint_as_float(kw[s] & 0xffff0000u);
            p += __shfl_xor(p, 1, 8);
            p += __shfl_xor(p, 2, 8);
            p += __shfl_xor(p, 4, 8);
            sc[s] = p;                   // all 8 lanes of the head hold the dot
        }
        float m = 0.f;
        #pragma unroll
        for (int s = 0; s < T; ++s) m = fmaxf(m, sc[s]);
        float den = __expf(-m);          // restricted-softmax null slot
        float mv0 = 0.f, mv1 = 0.f;
        #pragma unroll
        for (int s = 0; s < T; ++s) {
            float w = __expf(sc[s] - m);
            den += w;
            mv0 += w * __uint_as_float(vw[s] << 16);
            mv1 += w * __uint_as_float(vw[s] & 0xffff0000u);
        }
        float ws = __fdividef(nrm, den);
        acc0 += ws * mv0;
        acc1 += ws * mv1;
    }
    unsigned int o = ((unsigned int)f2bf(fmaxf(acc1, 0.f)) << 16)
                   |  (unsigned int)f2bf(fmaxf(acc0, 0.f));   // relu, packed bf16
    Xout[(size_t)n * 64 + ci] = o;
}

// ---------------- MFMA lin2 + fused log_softmax ----------------
// wave = 16 rows x 48 cols (3 N-tiles, cols 40..47 zero-padded in W2T).
// C layout: row=quad*4+reg, col=lane&15 -> a row's 16 cols live in one quad;
// cross-col reduce via width-16 shfl_xor.

__global__ __launch_bounds__(256) void k_lin2_mfma(const unsigned short* __restrict__ X,
                                                   const unsigned short* __restrict__ W2T,
                                                   const float* __restrict__ b2,
                                                   float* __restrict__ out) {
    int tid = threadIdx.x;
    int wid = tid >> 6, lane = tid & 63;
    int m = lane & 15, quad = lane >> 4;
    int rowA = blockIdx.x * 64 + wid * 16 + m;      // overread past N_NODES stays in ws
    bf16x8 af[4];
    const unsigned short* ap = X + (size_t)rowA * H_DIM + quad * 8;
    #pragma unroll
    for (int s = 0; s < 4; ++s)
        af[s] = __builtin_bit_cast(bf16x8, *(const uint4*)(ap + s * 32));

    f32x4 acc0 = {0.f, 0.f, 0.f, 0.f};
    f32x4 acc1 = {0.f, 0.f, 0.f, 0.f};
    f32x4 acc2 = {0.f, 0.f, 0.f, 0.f};
    const unsigned short* bp0 = W2T + (size_t)(m)      * H_DIM + quad * 8;
    const unsigned short* bp1 = W2T + (size_t)(16 + m) * H_DIM + quad * 8;
    const unsigned short* bp2 = W2T + (size_t)(32 + m) * H_DIM + quad * 8;
    #pragma unroll
    for (int s = 0; s < 4; ++s) {
        bf16x8 b0 = __builtin_bit_cast(bf16x8, *(const uint4*)(bp0 + s * 32));
        acc0 = __builtin_amdgcn_mfma_f32_16x16x32_bf16(af[s], b0, acc0, 0, 0, 0);
        bf16x8 b1 = __builtin_bit_cast(bf16x8, *(const uint4*)(bp1 + s * 32));
        acc1 = __builtin_amdgcn_mfma_f32_16x16x32_bf16(af[s], b1, acc1, 0, 0, 0);
        bf16x8 b2f = __builtin_bit_cast(bf16x8, *(const uint4*)(bp2 + s * 32));
        acc2 = __builtin_amdgcn_mfma_f32_16x16x32_bf16(af[s], b2f, acc2, 0, 0, 0);
    }

    float bb0 = b2[m], bb1 = b2[16 + m];
    float bb2 = (m < 8) ? b2[32 + m] : 0.f;
    int row0 = blockIdx.x * 64 + wid * 16 + quad * 4;
    #pragma unroll
    for (int rg = 0; rg < 4; ++rg) {
        int r = row0 + rg;
        float v0 = acc0[rg] + bb0;
        float v1 = acc1[rg] + bb1;
        float v2 = (m < 8) ? (acc2[rg] + bb2) : -INFINITY;
        float mx = fmaxf(fmaxf(v0, v1), v2);
        #pragma unroll
        for (int o = 8; o > 0; o >>= 1) mx = fmaxf(mx, __shfl_xor(mx, o, 16));
        float sm = __expf(v0 - mx) + __expf(v1 - mx) + ((m < 8) ? __expf(v2 - mx) : 0.f);
        #pragma unroll
        for (int o = 8; o > 0; o >>= 1) sm += __shfl_xor(sm, o, 16);
        float lse = mx + __logf(sm);
        if (r < N_NODES) {
            out[(size_t)r * C_OUTD + m]      = v0 - lse;
            out[(size_t)r * C_OUTD + 16 + m] = v1 - lse;
            if (m < 8) out[(size_t)r * C_OUTD + 32 + m] = v2 - lse;
        }
    }
}

// ---------------- launcher ----------------

extern "C" void kernel_launch(void* const* d_in, const int* in_sizes, int n_in,
                              void* d_out, int out_size, void* d_ws, size_t ws_size,
                              hipStream_t stream) {
    const int*   ei      = (const int*)d_in[0];
    const int*   row     = ei;
    const int*   col     = ei + NEDGES;
    const float* x_param = (const float*)d_in[1];
    const float* lin1_w  = (const float*)d_in[2];
    const float* lin1_b  = (const float*)d_in[3];
    const float* wq      = (const float*)d_in[4];
    const float* wk      = (const float*)d_in[5];
    const float* wv      = (const float*)d_in[6];
    const float* bq      = (const float*)d_in[7];
    const float* bk      = (const float*)d_in[8];
    const float* bv      = (const float*)d_in[9];
    const float* lin2_w  = (const float*)d_in[10];
    const float* lin2_b  = (const float*)d_in[11];
    float*       out     = (float*)d_out;

    char* wbase = (char*)d_ws;
    size_t off = 0;
    auto alloc = [&](size_t bytes) -> void* {
        off = (off + 255) & ~(size_t)255;
        void* p = wbase + off;
        off += bytes;
        return p;
    };
    int*            degi     = (int*)           alloc((size_t)N_NODES * 4);
    int*            offsets  = (int*)           alloc((size_t)N_NODES * 4);
    int*            cursor   = (int*)           alloc((size_t)N_NODES * 4);
    int*            csr_row  = (int*)           alloc((size_t)ETOT * 4);
    float*          csr_norm = (float*)         alloc((size_t)ETOT * 4);
    unsigned short* xpb      = (unsigned short*)alloc((size_t)N_NODES * F_IN_D * 2);
    unsigned short* W1T      = (unsigned short*)alloc((size_t)H_DIM * F_IN_D * 2);
    unsigned short* WTq      = (unsigned short*)alloc((size_t)3 * H_DIM * H_DIM * 2);
    unsigned short* WTk      = (unsigned short*)alloc((size_t)3 * H_DIM * H_DIM * 2);
    unsigned short* WTv      = (unsigned short*)alloc((size_t)3 * H_DIM * H_DIM * 2);
    unsigned short* W2T      = (unsigned short*)alloc((size_t)48 * H_DIM * 2);
    unsigned short* XHb      = (unsigned short*)alloc((size_t)4 * N_NODES * H_DIM * 2);
    float*          Qb       = (float*)         alloc((size_t)N_NODES * H_DIM * 4);
    unsigned short* Kb       = (unsigned short*)alloc((size_t)N_NODES * 3 * H_DIM * 2);
    unsigned short* Vb       = (unsigned short*)alloc((size_t)N_NODES * 3 * H_DIM * 2);

    // graph preprocessing (shared by all 3 layers)
    k_deg_init <<<(N_NODES + 255) / 256, 256, 0, stream>>>(degi);
    k_deg_count<<<(NEDGES + 255) / 256, 256, 0, stream>>>(col, degi);
    k_scan     <<<1, 256, 0, stream>>>(degi, offsets, cursor);
    k_scatter  <<<(ETOT + 255) / 256, 256, 0, stream>>>(row, col, degi, offsets, cursor,
                                                        csr_row, csr_norm);

    // bf16 casts
    k_cast_x<<<2500, 256, 0, stream>>>(x_param, xpb);
    k_cast_w<<<728, 256, 0, stream>>>(lin1_w, wq, wk, wv, lin2_w,
                                      W1T, WTq, WTk, WTv, W2T);

    // x0 = relu(x @ W1 + b1)  [MFMA, bf16 out]
    k_lin1_mfma<<<TILES_N, 256, 0, stream>>>(xpb, W1T, lin1_b, XHb, 8);

    for (int l = 0; l < 3; ++l) {
        int t = l + 1;
        k_qkv_mfma<<<(1 + 2 * t) * TILES_N, 256, 0, stream>>>(
            XHb, WTq + (size_t)l * 16384, WTk + (size_t)l * 16384, WTv + (size_t)l * 16384,
            bq + l * H_DIM, bk + l * H_DIM, bv + l * H_DIM,
            Qb, Kb, Vb, l, t, 8);
        unsigned int* Xnext = (unsigned int*)(XHb + (size_t)(l + 1) * N_NODES * H_DIM);
        if (t == 1)
            k_attn_agg<1><<<2500, 256, 0, stream>>>(Qb, (const unsigned int*)Kb,
                                                    (const unsigned int*)Vb, csr_row,
                                                    csr_norm, offsets, degi, Xnext);
        else if (t == 2)
            k_attn_agg<2><<<2500, 256, 0, stream>>>(Qb, (const unsigned int*)Kb,
                                                    (const unsigned int*)Vb, csr_row,
                                                    csr_norm, offsets, degi, Xnext);
        else
            k_attn_agg<3><<<2500, 256, 0, stream>>>(Qb, (const unsigned int*)Kb,
                                                    (const unsigned int*)Vb, csr_row,
                                                    csr_norm, offsets, degi, Xnext);
    }

    k_lin2_mfma<<<TILES_N, 256, 0, stream>>>(XHb + (size_t)3 * N_NODES * H_DIM,
                                             W2T, lin2_b, out);
}

// Round 12
// 272.795 us; speedup vs baseline: 9.4539x; 1.1431x over previous
//
#include <hip/hip_runtime.h>
#include <math.h>

#define N_NODES 10000
#define F_IN_D  256
#define H_DIM   128
#define C_OUTD  40
#define NHEADS  8
#define NEDGES  160000
#define ETOT    (NEDGES + N_NODES)
#define SCALE_F 0.25f  /* 1/sqrt(16) */
#define TILES_N 157    /* ceil(10000/64) */

typedef __attribute__((ext_vector_type(8))) short bf16x8;   // 8 bf16 = 4 VGPRs
typedef __attribute__((ext_vector_type(4))) float f32x4;
typedef __attribute__((ext_vector_type(2))) float f32x2;

__device__ __forceinline__ unsigned short f2bf(float f) {
    unsigned int u = __float_as_uint(f);
    unsigned int r = (u + 0x7FFFu + ((u >> 16) & 1u)) >> 16;  // RNE
    return (unsigned short)r;
}
__device__ __forceinline__ float bf2f(unsigned short h) {
    return __uint_as_float(((unsigned int)h) << 16);
}
__device__ __forceinline__ unsigned char f2fp8(float v) {
    int pk = __builtin_amdgcn_cvt_pk_fp8_f32(v, v, 0, false);  // OCP e4m3fn
    return (unsigned char)(pk & 0xff);
}

// ---------------- graph preprocessing ----------------

__global__ void k_deg_count(const int* __restrict__ col, int* degi) {
    int e = blockIdx.x * 256 + threadIdx.x;
    if (e < NEDGES) atomicAdd(&degi[col[e]], 1);
}

__global__ void k_scan(const int* __restrict__ degi, int* offsets, int* cursor) {
    __shared__ int part[256];
    int tid = threadIdx.x;
    int s = 0;
    if (tid < 250) {
        const int4* d4 = (const int4*)degi;
        for (int i = 0; i < 10; ++i) {
            int4 v = d4[tid * 10 + i];
            s += v.x + v.y + v.z + v.w;
        }
    }
    part[tid] = s;
    __syncthreads();
    for (int off = 1; off < 256; off <<= 1) {
        int v = 0;
        if (tid >= off) v = part[tid - off];
        __syncthreads();
        part[tid] += v;
        __syncthreads();
    }
    if (tid < 250) {
        int base = part[tid] - s;  // exclusive prefix
        int beg = tid * 40;
        for (int i = 0; i < 40; ++i) {
            offsets[beg + i] = base;
            cursor[beg + i]  = 0;
            base += degi[beg + i];
        }
    }
}

__global__ void k_scatter(const int* __restrict__ row, const int* __restrict__ col,
                          const int* __restrict__ degi, const int* __restrict__ offsets,
                          int* cursor, int* csr_row, float* csr_norm) {
    int e = blockIdx.x * 256 + threadIdx.x;
    if (e >= ETOT) return;
    int r, c;
    if (e < NEDGES) { r = row[e]; c = col[e]; }
    else            { r = c = e - NEDGES; }   // self-loop
    int slot = offsets[c] + atomicAdd(&cursor[c], 1);
    float dr = rsqrtf((float)degi[r]);
    float dc = rsqrtf((float)degi[c]);
    csr_row[slot]  = r;
    csr_norm[slot] = dr * dc;
}

// ---------------- fused prep: deg_init + x cast + weight casts (independent) ----
// b<2500: cast x_param (fp32->bf16, 4 elems/thread);
// 2500<=b<3228: transpose+cast weights; b>=3228: degi=1.

__global__ void k_prep(const float* __restrict__ x, unsigned short* __restrict__ xb,
                       const float* __restrict__ w1, const float* __restrict__ wq,
                       const float* __restrict__ wk, const float* __restrict__ wv,
                       const float* __restrict__ w2,
                       unsigned short* __restrict__ W1T, unsigned short* __restrict__ WTq,
                       unsigned short* __restrict__ WTk, unsigned short* __restrict__ WTv,
                       unsigned short* __restrict__ W2T, int* __restrict__ degi) {
    int b = blockIdx.x;
    if (b < 2500) {
        int i = b * 256 + threadIdx.x;       // 2500*256*4 == 2560000 exactly
        float4 v = *(const float4*)&x[(size_t)i * 4];
        ushort4 o;
        o.x = f2bf(v.x); o.y = f2bf(v.y); o.z = f2bf(v.z); o.w = f2bf(v.w);
        *(ushort4*)&xb[(size_t)i * 4] = o;
    } else if (b < 3228) {
        int e = (b - 2500) * 256 + threadIdx.x;
        if (e < 32768) {
            int n = e >> 8, k = e & 255;
            W1T[e] = f2bf(w1[k * H_DIM + n]);
        } else if (e < 180224) {
            int e2 = e - 32768;
            int mat = e2 >> 14;          // 0..8
            int r   = e2 & 16383;
            int n = r >> 7, k = r & 127;
            int l = mat / 3, ws = mat % 3;
            const float*    src = (ws == 0) ? wq  : (ws == 1) ? wk  : wv;
            unsigned short* dst = (ws == 0) ? WTq : (ws == 1) ? WTk : WTv;
            dst[l * 16384 + n * H_DIM + k] = f2bf(src[l * 16384 + k * H_DIM + n]);
        } else if (e < 186368) {
            int e3 = e - 180224;
            int c = e3 >> 7, k = e3 & 127;
            W2T[c * H_DIM + k] = (c < C_OUTD) ? f2bf(w2[k * C_OUTD + c]) : 0;
        }
    } else {
        int i = (b - 3228) * 256 + threadIdx.x;
        if (i < N_NODES) degi[i] = 1;    // self-loop
    }
}

// ---------------- MFMA lin1: X0 = relu(x_bf @ W1 + b1), bf16 out ----------------
// LDS-free: A-frags (A[m=lane&15][k=quad*8+j]) and B-frags (WT[n][k]) straight
// from global via uint4. nct is a RUNTIME arg (=8): unknown trip count prevents
// the full-unroll VGPR spill seen in round 3.

__global__ __launch_bounds__(256) void k_lin1_mfma(const unsigned short* __restrict__ Xb,
                                                   const unsigned short* __restrict__ W1T,
                                                   const float* __restrict__ b1,
                                                   unsigned short* __restrict__ X0,
                                                   int nct) {
    int tid = threadIdx.x;
    int wid = tid >> 6, lane = tid & 63;
    int m = lane & 15, quad = lane >> 4;
    int rowA = blockIdx.x * 64 + wid * 16 + m;      // A overread past N_NODES stays in ws
    bf16x8 af[8];
    const unsigned short* ap = Xb + (size_t)rowA * F_IN_D + quad * 8;
    #pragma unroll
    for (int s = 0; s < 8; ++s)
        af[s] = __builtin_bit_cast(bf16x8, *(const uint4*)(ap + s * 32));
    int row0 = blockIdx.x * 64 + wid * 16 + quad * 4;
    for (int ct = 0; ct < nct; ++ct) {
        int col = ct * 16 + m;
        const unsigned short* bp = W1T + (size_t)col * F_IN_D + quad * 8;
        f32x4 acc = {0.f, 0.f, 0.f, 0.f};
        #pragma unroll
        for (int s = 0; s < 8; ++s) {
            bf16x8 bfr = __builtin_bit_cast(bf16x8, *(const uint4*)(bp + s * 32));
            acc = __builtin_amdgcn_mfma_f32_16x16x32_bf16(af[s], bfr, acc, 0, 0, 0);
        }
        float bb = b1[col];
        #pragma unroll
        for (int rg = 0; rg < 4; ++rg) {
            int r = row0 + rg;
            if (r < N_NODES)
                X0[(size_t)r * H_DIM + col] = f2bf(fmaxf(acc[rg] + bb, 0.f));
        }
    }
}

// ---------------- MFMA fused QKV projection ----------------
// grid = (1+2t)*TILES_N; mode 0 = Q (fp32 out), 1..t = K slices, t+1..2t = V.
// K/V: fp8 e4m3, layout [node][slice(3)][128] (byte stores in epilogue).

__global__ __launch_bounds__(256) void k_qkv_mfma(const unsigned short* __restrict__ XHb,
                                                  const unsigned short* __restrict__ WTq,
                                                  const unsigned short* __restrict__ WTk,
                                                  const unsigned short* __restrict__ WTv,
                                                  const float* __restrict__ bq,
                                                  const float* __restrict__ bk,
                                                  const float* __restrict__ bv,
                                                  float* __restrict__ Qb,
                                                  unsigned char* __restrict__ Kb,
                                                  unsigned char* __restrict__ Vb,
                                                  int l, int t, int nct) {
    int tid = threadIdx.x;
    int wid = tid >> 6, lane = tid & 63;
    int m = lane & 15, quad = lane >> 4;
    int mi = blockIdx.x / TILES_N;
    int rt = blockIdx.x % TILES_N;
    const unsigned short* WT; const float* bias; int slice, mode;
    if (mi == 0)      { WT = WTq; bias = bq; slice = l;          mode = 0; }
    else if (mi <= t) { WT = WTk; bias = bk; slice = mi - 1;     mode = 1; }
    else              { WT = WTv; bias = bv; slice = mi - t - 1; mode = 2; }
    const unsigned short* A = XHb + (size_t)slice * N_NODES * H_DIM;
    int rowA = rt * 64 + wid * 16 + m;
    bf16x8 af[4];
    const unsigned short* ap = A + (size_t)rowA * H_DIM + quad * 8;
    #pragma unroll
    for (int s = 0; s < 4; ++s)
        af[s] = __builtin_bit_cast(bf16x8, *(const uint4*)(ap + s * 32));
    int row0 = rt * 64 + wid * 16 + quad * 4;
    unsigned char* OutB = (mode == 1) ? Kb : Vb;
    for (int ct = 0; ct < nct; ++ct) {
        int col = ct * 16 + m;
        const unsigned short* bp = WT + (size_t)col * H_DIM + quad * 8;
        f32x4 acc = {0.f, 0.f, 0.f, 0.f};
        #pragma unroll
        for (int s = 0; s < 4; ++s) {
            bf16x8 bfr = __builtin_bit_cast(bf16x8, *(const uint4*)(bp + s * 32));
            acc = __builtin_amdgcn_mfma_f32_16x16x32_bf16(af[s], bfr, acc, 0, 0, 0);
        }
        float bb = bias[col];
        #pragma unroll
        for (int rg = 0; rg < 4; ++rg) {
            int r = row0 + rg;
            if (r < N_NODES) {
                float v = acc[rg] + bb;
                if (mode == 0) Qb[(size_t)r * H_DIM + col] = v;
                else OutB[((size_t)r * 3 + slice) * H_DIM + col] = f2fp8(v);
            }
        }
    }
}

// ---------------- fused per-node attention aggregation (wave-per-node) ----------------
// 256 threads = 4 waves = 4 nodes. fp8 K/V: 4 dims/lane (one uint), 32 lanes
// cover 128 dims -> TWO edges per wave-iteration (half = lane>>5).
// head h = (lane&31)>>2, reduction width 4; cross-half combine at end.
// K,V viewed as uint [node][slice(3)][32].

template <int T>
__global__ __launch_bounds__(256) void k_attn_agg(const float* __restrict__ Q,
                                                  const unsigned int* __restrict__ K,
                                                  const unsigned int* __restrict__ V,
                                                  const int* __restrict__ csr_row,
                                                  const float* __restrict__ csr_norm,
                                                  const int* __restrict__ offsets,
                                                  const int* __restrict__ degi,
                                                  unsigned int* __restrict__ Xout) {
    int tid = threadIdx.x;
    int wid = tid >> 6, lane = tid & 63;
    int half = lane >> 5, ci = lane & 31;
    int n = blockIdx.x * 4 + wid;        // grid 2500*4 == N_NODES exactly
    f32x4 q4;
    {
        float4 t4 = *(const float4*)&Q[(size_t)n * H_DIM + ci * 4];
        q4[0] = t4.x * SCALE_F; q4[1] = t4.y * SCALE_F;
        q4[2] = t4.z * SCALE_F; q4[3] = t4.w * SCALE_F;
    }
    int start = offsets[n];
    int cnt   = degi[n];
    int npairs = (cnt + 1) >> 1;
    float a0 = 0.f, a1 = 0.f, a2 = 0.f, a3 = 0.f;

    for (int j = 0; j < npairs; ++j) {
        int j2 = j * 2 + half;
        int valid = j2 < cnt;
        int idx = start + (valid ? j2 : 0);
        int   r   = csr_row[idx];
        float nrm = valid ? csr_norm[idx] : 0.f;
        const unsigned int* kp = K + (size_t)r * 96 + ci;
        const unsigned int* vp = V + (size_t)r * 96 + ci;
        unsigned int kw[T], vw[T];
        #pragma unroll
        for (int s = 0; s < T; ++s) { kw[s] = kp[s * 32]; vw[s] = vp[s * 32]; }
        float sc[T];
        #pragma unroll
        for (int s = 0; s < T; ++s) {
            f32x2 klo = __builtin_amdgcn_cvt_pk_f32_fp8(kw[s], false);
            f32x2 khi = __builtin_amdgcn_cvt_pk_f32_fp8(kw[s], true);
            float p = q4[0] * klo[0] + q4[1] * klo[1] + q4[2] * khi[0] + q4[3] * khi[1];
            p += __shfl_xor(p, 1, 4);
            p += __shfl_xor(p, 2, 4);
            sc[s] = p;                   // all 4 lanes of the head hold the dot
        }
        float m = 0.f;
        #pragma unroll
        for (int s = 0; s < T; ++s) m = fmaxf(m, sc[s]);
        float den = __expf(-m);          // restricted-softmax null slot
        float mv0 = 0.f, mv1 = 0.f, mv2 = 0.f, mv3 = 0.f;
        #pragma unroll
        for (int s = 0; s < T; ++s) {
            float w = __expf(sc[s] - m);
            den += w;
            f32x2 vlo = __builtin_amdgcn_cvt_pk_f32_fp8(vw[s], false);
            f32x2 vhi = __builtin_amdgcn_cvt_pk_f32_fp8(vw[s], true);
            mv0 += w * vlo[0]; mv1 += w * vlo[1];
            mv2 += w * vhi[0]; mv3 += w * vhi[1];
        }
        float ws = __fdividef(nrm, den);
        a0 += ws * mv0; a1 += ws * mv1; a2 += ws * mv2; a3 += ws * mv3;
    }
    // combine the two edge-halves
    a0 += __shfl_xor(a0, 32, 64);
    a1 += __shfl_xor(a1, 32, 64);
    a2 += __shfl_xor(a2, 32, 64);
    a3 += __shfl_xor(a3, 32, 64);
    if (half == 0) {
        uint2 o;
        o.x = ((unsigned int)f2bf(fmaxf(a1, 0.f)) << 16) | (unsigned int)f2bf(fmaxf(a0, 0.f));
        o.y = ((unsigned int)f2bf(fmaxf(a3, 0.f)) << 16) | (unsigned int)f2bf(fmaxf(a2, 0.f));
        *(uint2*)&Xout[(size_t)n * 64 + ci * 2] = o;   // relu, packed bf16
    }
}

// ---------------- MFMA lin2 + fused log_softmax ----------------
// wave = 16 rows x 48 cols (3 N-tiles, cols 40..47 zero-padded in W2T).
// C layout: row=quad*4+reg, col=lane&15 -> a row's 16 cols live in one quad;
// cross-col reduce via width-16 shfl_xor.

__global__ __launch_bounds__(256) void k_lin2_mfma(const unsigned short* __restrict__ X,
                                                   const unsigned short* __restrict__ W2T,
                                                   const float* __restrict__ b2,
                                                   float* __restrict__ out) {
    int tid = threadIdx.x;
    int wid = tid >> 6, lane = tid & 63;
    int m = lane & 15, quad = lane >> 4;
    int rowA = blockIdx.x * 64 + wid * 16 + m;      // overread past N_NODES stays in ws
    bf16x8 af[4];
    const unsigned short* ap = X + (size_t)rowA * H_DIM + quad * 8;
    #pragma unroll
    for (int s = 0; s < 4; ++s)
        af[s] = __builtin_bit_cast(bf16x8, *(const uint4*)(ap + s * 32));

    f32x4 acc0 = {0.f, 0.f, 0.f, 0.f};
    f32x4 acc1 = {0.f, 0.f, 0.f, 0.f};
    f32x4 acc2 = {0.f, 0.f, 0.f, 0.f};
    const unsigned short* bp0 = W2T + (size_t)(m)      * H_DIM + quad * 8;
    const unsigned short* bp1 = W2T + (size_t)(16 + m) * H_DIM + quad * 8;
    const unsigned short* bp2 = W2T + (size_t)(32 + m) * H_DIM + quad * 8;
    #pragma unroll
    for (int s = 0; s < 4; ++s) {
        bf16x8 b0 = __builtin_bit_cast(bf16x8, *(const uint4*)(bp0 + s * 32));
        acc0 = __builtin_amdgcn_mfma_f32_16x16x32_bf16(af[s], b0, acc0, 0, 0, 0);
        bf16x8 b1 = __builtin_bit_cast(bf16x8, *(const uint4*)(bp1 + s * 32));
        acc1 = __builtin_amdgcn_mfma_f32_16x16x32_bf16(af[s], b1, acc1, 0, 0, 0);
        bf16x8 b2f = __builtin_bit_cast(bf16x8, *(const uint4*)(bp2 + s * 32));
        acc2 = __builtin_amdgcn_mfma_f32_16x16x32_bf16(af[s], b2f, acc2, 0, 0, 0);
    }

    float bb0 = b2[m], bb1 = b2[16 + m];
    float bb2 = (m < 8) ? b2[32 + m] : 0.f;
    int row0 = blockIdx.x * 64 + wid * 16 + quad * 4;
    #pragma unroll
    for (int rg = 0; rg < 4; ++rg) {
        int r = row0 + rg;
        float v0 = acc0[rg] + bb0;
        float v1 = acc1[rg] + bb1;
        float v2 = (m < 8) ? (acc2[rg] + bb2) : -INFINITY;
        float mx = fmaxf(fmaxf(v0, v1), v2);
        #pragma unroll
        for (int o = 8; o > 0; o >>= 1) mx = fmaxf(mx, __shfl_xor(mx, o, 16));
        float sm = __expf(v0 - mx) + __expf(v1 - mx) + ((m < 8) ? __expf(v2 - mx) : 0.f);
        #pragma unroll
        for (int o = 8; o > 0; o >>= 1) sm += __shfl_xor(sm, o, 16);
        float lse = mx + __logf(sm);
        if (r < N_NODES) {
            out[(size_t)r * C_OUTD + m]      = v0 - lse;
            out[(size_t)r * C_OUTD + 16 + m] = v1 - lse;
            if (m < 8) out[(size_t)r * C_OUTD + 32 + m] = v2 - lse;
        }
    }
}

// ---------------- launcher ----------------

extern "C" void kernel_launch(void* const* d_in, const int* in_sizes, int n_in,
                              void* d_out, int out_size, void* d_ws, size_t ws_size,
                              hipStream_t stream) {
    const int*   ei      = (const int*)d_in[0];
    const int*   row     = ei;
    const int*   col     = ei + NEDGES;
    const float* x_param = (const float*)d_in[1];
    const float* lin1_w  = (const float*)d_in[2];
    const float* lin1_b  = (const float*)d_in[3];
    const float* wq      = (const float*)d_in[4];
    const float* wk      = (const float*)d_in[5];
    const float* wv      = (const float*)d_in[6];
    const float* bq      = (const float*)d_in[7];
    const float* bk      = (const float*)d_in[8];
    const float* bv      = (const float*)d_in[9];
    const float* lin2_w  = (const float*)d_in[10];
    const float* lin2_b  = (const float*)d_in[11];
    float*       out     = (float*)d_out;

    char* wbase = (char*)d_ws;
    size_t off = 0;
    auto alloc = [&](size_t bytes) -> void* {
        off = (off + 255) & ~(size_t)255;
        void* p = wbase + off;
        off += bytes;
        return p;
    };
    int*            degi     = (int*)           alloc((size_t)N_NODES * 4);
    int*            offsets  = (int*)           alloc((size_t)N_NODES * 4);
    int*            cursor   = (int*)           alloc((size_t)N_NODES * 4);
    int*            csr_row  = (int*)           alloc((size_t)ETOT * 4);
    float*          csr_norm = (float*)         alloc((size_t)ETOT * 4);
    unsigned short* xpb      = (unsigned short*)alloc((size_t)N_NODES * F_IN_D * 2);
    unsigned short* W1T      = (unsigned short*)alloc((size_t)H_DIM * F_IN_D * 2);
    unsigned short* WTq      = (unsigned short*)alloc((size_t)3 * H_DIM * H_DIM * 2);
    unsigned short* WTk      = (unsigned short*)alloc((size_t)3 * H_DIM * H_DIM * 2);
    unsigned short* WTv      = (unsigned short*)alloc((size_t)3 * H_DIM * H_DIM * 2);
    unsigned short* W2T      = (unsigned short*)alloc((size_t)48 * H_DIM * 2);
    unsigned short* XHb      = (unsigned short*)alloc((size_t)4 * N_NODES * H_DIM * 2);
    float*          Qb       = (float*)         alloc((size_t)N_NODES * H_DIM * 4);
    unsigned char*  Kb       = (unsigned char*) alloc((size_t)N_NODES * 3 * H_DIM);
    unsigned char*  Vb       = (unsigned char*) alloc((size_t)N_NODES * 3 * H_DIM);

    // fused prep: x cast + weight casts + deg init (independent tasks)
    k_prep<<<3268, 256, 0, stream>>>(x_param, xpb, lin1_w, wq, wk, wv, lin2_w,
                                     W1T, WTq, WTk, WTv, W2T, degi);
    k_deg_count<<<(NEDGES + 255) / 256, 256, 0, stream>>>(col, degi);
    k_scan     <<<1, 256, 0, stream>>>(degi, offsets, cursor);
    k_scatter  <<<(ETOT + 255) / 256, 256, 0, stream>>>(row, col, degi, offsets, cursor,
                                                        csr_row, csr_norm);

    // x0 = relu(x @ W1 + b1)  [MFMA, bf16 out]
    k_lin1_mfma<<<TILES_N, 256, 0, stream>>>(xpb, W1T, lin1_b, XHb, 8);

    for (int l = 0; l < 3; ++l) {
        int t = l + 1;
        k_qkv_mfma<<<(1 + 2 * t) * TILES_N, 256, 0, stream>>>(
            XHb, WTq + (size_t)l * 16384, WTk + (size_t)l * 16384, WTv + (size_t)l * 16384,
            bq + l * H_DIM, bk + l * H_DIM, bv + l * H_DIM,
            Qb, Kb, Vb, l, t, 8);
        unsigned int* Xnext = (unsigned int*)(XHb + (size_t)(l + 1) * N_NODES * H_DIM);
        if (t == 1)
            k_attn_agg<1><<<2500, 256, 0, stream>>>(Qb, (const unsigned int*)Kb,
                                                    (const unsigned int*)Vb, csr_row,
                                                    csr_norm, offsets, degi, Xnext);
        else if (t == 2)
            k_attn_agg<2><<<2500, 256, 0, stream>>>(Qb, (const unsigned int*)Kb,
                                                    (const unsigned int*)Vb, csr_row,
                                                    csr_norm, offsets, degi, Xnext);
        else
            k_attn_agg<3><<<2500, 256, 0, stream>>>(Qb, (const unsigned int*)Kb,
                                                    (const unsigned int*)Vb, csr_row,
                                                    csr_norm, offsets, degi, Xnext);
    }

    k_lin2_mfma<<<TILES_N, 256, 0, stream>>>(XHb + (size_t)3 * N_NODES * H_DIM,
                                             W2T, lin2_b, out);
}